// Round 12
// baseline (262.587 us; speedup 1.0000x reference)
//
#include <hip/hip_runtime.h>

typedef unsigned short ushortT;
typedef __bf16 bf16x8 __attribute__((ext_vector_type(8)));
typedef float f32x4 __attribute__((ext_vector_type(4)));

// Problem constants
#define BB   2
#define LL   2048
#define DM   768
#define HH   12
#define FT   16
#define HD   64
#define DEXP 273      // 1 + 16 + 256
#define CH   128      // chunk length
#define NC   16       // chunks per sequence (LL/CH)
#define NBH  24       // BB*HH
#define NBLK 384      // NBH*NC
#define C2f  0.17677669529663687f   // 1/(4*sqrt(2))
#define KH   768      // K per half
#define KP   1536     // packed row length: [hi(768) | lo(768)]
// packed-G geometry: per (bh,chunk): 9 slabs x [64 e][hi fi0..31 | lo fi0..31] ushorts,
// XOR-swizzled: 16B granule g within a 128B e-row lives at g^(e&7).
#define SLAB_US   4096     // ushorts per slab page (64*64)
#define SPK_BLK_US 36864   // 9 slabs
#define SPK_BLK_B  73728

// ---------------- split helpers ----------------
__device__ __forceinline__ void split_bf16(float x, ushortT& hi, ushortT& lo) {
  unsigned b = __float_as_uint(x);
  unsigned r = b + 0x7FFFu + ((b >> 16) & 1u);  // RNE to bf16
  hi = (ushortT)(r >> 16);
  float hf = __uint_as_float((unsigned)hi << 16);
  lo = (ushortT)(__float_as_uint(x - hf) >> 16);  // truncate
}

// X [M][768] f32 -> Xh [M][1536] bf16 = [hi | lo]
__global__ __launch_bounds__(256) void pack_a(const float* __restrict__ X,
                                              ushortT* __restrict__ Xh,
                                              int total4) {
  int g = blockIdx.x * 256 + threadIdx.x;
  if (g >= total4) return;
  int m = g / 192, k4 = (g % 192) * 4;
  float4 v = *(const float4*)(X + (size_t)m * 768 + k4);
  ushortT h[4], l[4];
  split_bf16(v.x, h[0], l[0]);
  split_bf16(v.y, h[1], l[1]);
  split_bf16(v.z, h[2], l[2]);
  split_bf16(v.w, h[3], l[3]);
  ushortT* p = Xh + (size_t)m * KP + k4;
  *(ushort4*)p = *(ushort4*)h;
  *(ushort4*)(p + KH) = *(ushort4*)l;
}

// W rows (selected from W0/W1/W2) -> Wh [N][1536] bf16 = [hi | lo]
__global__ __launch_bounds__(256) void pack_w(const float* __restrict__ W0,
                                              const float* __restrict__ W1,
                                              const float* __restrict__ W2,
                                              int n1, int n2,
                                              ushortT* __restrict__ Wh,
                                              int total4) {
  int g = blockIdx.x * 256 + threadIdx.x;
  if (g >= total4) return;
  int n = g / 192, k4 = (g % 192) * 4;
  const float* src = (n < n1 ? W0 + (size_t)n * 768
                    : n < n2 ? W1 + (size_t)(n - n1) * 768
                             : W2 + (size_t)(n - n2) * 768);
  float4 v = *(const float4*)(src + k4);
  ushortT h[4], l[4];
  split_bf16(v.x, h[0], l[0]);
  split_bf16(v.y, h[1], l[1]);
  split_bf16(v.z, h[2], l[2]);
  split_bf16(v.w, h[3], l[3]);
  ushortT* p = Wh + (size_t)n * KP + k4;
  *(ushort4*)p = *(ushort4*)h;
  *(ushort4*)(p + KH) = *(ushort4*)l;
}

// async global->LDS, 16B per lane; lds base must be wave-uniform (lane*16 implicit)
typedef const __attribute__((address_space(1))) unsigned gq_t;
typedef __attribute__((address_space(3))) unsigned lq_t;
__device__ __forceinline__ void gload_lds16(const ushortT* g, ushortT* l) {
  __builtin_amdgcn_global_load_lds((gq_t*)g, (lq_t*)l, 16, 0, 0);
}

// ---------------- MFMA GEMM: Y[M][N] = A[M][KP] @ B[N][KP]^T (3-term split-bf16) -------
// R12: R9 structure (512 thr / 8 waves, 128x64 tile, 2-phase dbuf, one barrier/step)
// + GRANULE-MAJOR LDS layout: granule g of row r lives at g*256B + r*16B within each
// 16-row block (staged via pre-swizzled global lane mapping: row=lane&15, g=lane>>4;
// LDS dest stays linear). Read bank = fr*4%32 -> 2-way (free) instead of the
// row-major layout's 8-way conflict (row stride 64B aliases 2x in 128B bank space).
__global__ __launch_bounds__(512, 4) void mfma_gemm(const ushortT* __restrict__ A,
                                                    const ushortT* __restrict__ B,
                                                    float* __restrict__ Y, int ldy,
                                                    int ntiles) {
  __shared__ ushortT sAh[2][4096], sAl[2][4096];
  __shared__ ushortT sBh[2][2048], sBl[2][2048];
  const int blk = blockIdx.x;
  const int xcd = blk & 7, slot = blk >> 3;
  const int mtp = gridDim.x / (8 * ntiles);
  const int mt = xcd * mtp + slot / ntiles;
  const int nt = slot % ntiles;
  const int bm = mt * 128, bn = nt * 64;
  const int tid = threadIdx.x, wave = tid >> 6, lane = tid & 63;
  const int srow = lane & 15, sg8 = (lane >> 4) * 8;  // granule-major lane mapping
  const ushortT* gsrc;
  ushortT* lb0;
  ushortT* lb1;
  int iters;
  switch (wave) {
    case 0:  gsrc = A + (size_t)(bm + srow) * KP + sg8;           lb0 = sAh[0];        lb1 = sAh[1];        iters = 4; break;
    case 1:  gsrc = A + (size_t)(bm + 64 + srow) * KP + sg8;      lb0 = sAh[0] + 2048; lb1 = sAh[1] + 2048; iters = 4; break;
    case 2:  gsrc = A + (size_t)(bm + srow) * KP + KH + sg8;      lb0 = sAl[0];        lb1 = sAl[1];        iters = 4; break;
    case 3:  gsrc = A + (size_t)(bm + 64 + srow) * KP + KH + sg8; lb0 = sAl[0] + 2048; lb1 = sAl[1] + 2048; iters = 4; break;
    case 4:  gsrc = B + (size_t)(bn + srow) * KP + sg8;           lb0 = sBh[0];        lb1 = sBh[1];        iters = 2; break;
    case 5:  gsrc = B + (size_t)(bn + 32 + srow) * KP + sg8;      lb0 = sBh[0] + 1024; lb1 = sBh[1] + 1024; iters = 2; break;
    case 6:  gsrc = B + (size_t)(bn + srow) * KP + KH + sg8;      lb0 = sBl[0];        lb1 = sBl[1];        iters = 2; break;
    default: gsrc = B + (size_t)(bn + 32 + srow) * KP + KH + sg8; lb0 = sBl[0] + 1024; lb1 = sBl[1] + 1024; iters = 2; break;
  }
  const int wm = (wave >> 1) * 32, wn = (wave & 1) * 32;
  const int wmb = (wave >> 1) * 2, wnb = (wave & 1) * 2;  // 16-row block indices
  const int fr = lane & 15, quad = lane >> 4;
  f32x4 acc[2][2] = {};
  // prologue: stage K-step 0 into buffer 0
  for (int it = 0; it < iters; it++)
    gload_lds16(gsrc + (size_t)it * 16 * KP, lb0 + it * 512);
  __syncthreads();  // vmcnt(0) drain: step-0 tiles landed
#pragma unroll 2
  for (int step = 0; step < 24; step++) {
    const int cur = step & 1;
    // prefetch next K-step into the other buffer (in flight across compute)
    if (step < 23) {
      ushortT* lbn = cur ? lb0 : lb1;
      const int k1 = (step + 1) * 32;
      for (int it = 0; it < iters; it++)
        gload_lds16(gsrc + k1 + (size_t)it * 16 * KP, lbn + it * 512);
    }
    const ushortT* pAh = sAh[cur];
    const ushortT* pAl = sAl[cur];
    const ushortT* pBh = sBh[cur];
    const ushortT* pBl = sBl[cur];
    bf16x8 ah[2], al[2], bh2[2], bl2[2];
#pragma unroll
    for (int mi = 0; mi < 2; mi++) {
      ah[mi] = *(const bf16x8*)&pAh[(wmb + mi) * 512 + quad * 128 + fr * 8];
      al[mi] = *(const bf16x8*)&pAl[(wmb + mi) * 512 + quad * 128 + fr * 8];
    }
#pragma unroll
    for (int ni = 0; ni < 2; ni++) {
      bh2[ni] = *(const bf16x8*)&pBh[(wnb + ni) * 512 + quad * 128 + fr * 8];
      bl2[ni] = *(const bf16x8*)&pBl[(wnb + ni) * 512 + quad * 128 + fr * 8];
    }
#pragma unroll
    for (int mi = 0; mi < 2; mi++)
#pragma unroll
      for (int ni = 0; ni < 2; ni++) {
        acc[mi][ni] = __builtin_amdgcn_mfma_f32_16x16x32_bf16(ah[mi], bh2[ni], acc[mi][ni], 0, 0, 0);
        acc[mi][ni] = __builtin_amdgcn_mfma_f32_16x16x32_bf16(ah[mi], bl2[ni], acc[mi][ni], 0, 0, 0);
        acc[mi][ni] = __builtin_amdgcn_mfma_f32_16x16x32_bf16(al[mi], bh2[ni], acc[mi][ni], 0, 0, 0);
      }
    __syncthreads();  // drains vmcnt(0): next-step tiles landed; cur reads done
  }
  const int orow = quad * 4;
#pragma unroll
  for (int mi = 0; mi < 2; mi++)
#pragma unroll
    for (int ni = 0; ni < 2; ni++) {
      float* yp = Y + (size_t)(bm + wm + mi * 16 + orow) * ldy + bn + wn + ni * 16 + fr;
#pragma unroll
      for (int r = 0; r < 4; r++) yp[(size_t)r * ldy] = acc[mi][ni][r];
    }
}

// ---------------- K2: Spk = phi_k^T @ V via MFMA, written packed/transposed/swizzled ----
// R8: 512 threads / 8 waves. phi build split 2 threads/row (VALU halves); MFMA
// retiled 18 row-tiles x 4 col-tiles over 8 waves (9 tiles each, acc[9]).
__global__ __launch_bounds__(512, 4) void chunk_sum_kernel(
    const float* __restrict__ qkv, ushortT* __restrict__ Spk,
    float* __restrict__ csk) {
  const int blk = blockIdx.x;
  const int bh = blk >> 4, c = blk & 15;
  const int b = bh / HH, h = bh % HH;
  __shared__ float kT[16][128];
  __shared__ ushortT phiA[288][72];
  __shared__ ushortT Vt[64][72];
  const float* base = qkv + (size_t)(b * LL + c * CH) * 1152;
  const int tid = threadIdx.x;
  const int wave = tid >> 6, lane = tid & 63;
  const int fr = lane & 15, quad = lane >> 4;
  // kT load: one item per thread (512 items)
  {
    const int m = tid >> 2, i4 = (tid & 3) * 4;
    float4 k4 = *(const float4*)&base[(size_t)m * 1152 + 192 + h * 16 + i4];
    kT[i4 + 0][m] = k4.x; kT[i4 + 1][m] = k4.y;
    kT[i4 + 2][m] = k4.z; kT[i4 + 3][m] = k4.w;
  }
  const int wm2 = (wave & 1) * 144;   // row half: 9 tiles of 16
  const int wn2 = (wave >> 1) * 16;   // col tile: 16 e
  f32x4 acc[9] = {};
  __syncthreads();
#pragma unroll 1
  for (int s = 0; s < 4; s++) {
    const int m0 = s * 32;
    if (s) __syncthreads();
    // Vt stage: one item per thread (512 items)
    {
      const int m = m0 + (tid >> 4), e4 = (tid & 15) * 4;
      float4 v4 = *(const float4*)&base[(size_t)m * 1152 + 384 + h * 64 + e4];
      ushortT hh[4], ll[4];
      split_bf16(v4.x, hh[0], ll[0]); split_bf16(v4.y, hh[1], ll[1]);
      split_bf16(v4.z, hh[2], ll[2]); split_bf16(v4.w, hh[3], ll[3]);
      const int mi2 = m - m0;
#pragma unroll
      for (int j = 0; j < 4; j++) {
        Vt[e4 + j][mi2] = hh[j];
        Vt[e4 + j][32 + mi2] = ll[j];
      }
    }
    // phi build: 576 half-rows (2 threads per feature row, 16 m-values each)
    for (int idx = tid; idx < 576; idx += 512) {
      const int f = idx >> 1, hf = (idx & 1) * 16;
      const float* pa = (f >= 17) ? kT[(f - 17) >> 4] : (f >= 1 ? kT[f - 1] : kT[0]);
      const float* pb = (f >= 17) ? kT[(f - 17) & 15] : kT[0];
      const float sc = (f == 0) ? 1.0f : (f < 17 ? 0.5f : C2f);
      const bool quadf = (f >= 17);
      const bool valid = (f < DEXP);
      ushortT hrow[16], lrow[16];
#pragma unroll
      for (int g = 0; g < 4; g++) {
        float4 a4 = *(const float4*)&pa[m0 + hf + g * 4];
        float4 b4 = *(const float4*)&pb[m0 + hf + g * 4];
        float v0, v1, v2, v3;
        if (f == 0) {
          v0 = v1 = v2 = v3 = 1.0f;
        } else if (!quadf) {
          v0 = sc * a4.x; v1 = sc * a4.y; v2 = sc * a4.z; v3 = sc * a4.w;
        } else {
          v0 = sc * a4.x * b4.x; v1 = sc * a4.y * b4.y;
          v2 = sc * a4.z * b4.z; v3 = sc * a4.w * b4.w;
        }
        if (!valid) { v0 = v1 = v2 = v3 = 0.0f; }
        split_bf16(v0, hrow[g * 4 + 0], lrow[g * 4 + 0]);
        split_bf16(v1, hrow[g * 4 + 1], lrow[g * 4 + 1]);
        split_bf16(v2, hrow[g * 4 + 2], lrow[g * 4 + 2]);
        split_bf16(v3, hrow[g * 4 + 3], lrow[g * 4 + 3]);
      }
      *(uint4*)&phiA[f][hf] = *(uint4*)&hrow[0];
      *(uint4*)&phiA[f][hf + 8] = *(uint4*)&hrow[8];
      *(uint4*)&phiA[f][32 + hf] = *(uint4*)&lrow[0];
      *(uint4*)&phiA[f][32 + hf + 8] = *(uint4*)&lrow[8];
    }
    __syncthreads();
    bf16x8 bhf = *(const bf16x8*)&Vt[wn2 + fr][quad * 8];
    bf16x8 blf = *(const bf16x8*)&Vt[wn2 + fr][32 + quad * 8];
#pragma unroll
    for (int mi = 0; mi < 9; mi++) {
      bf16x8 ah = *(const bf16x8*)&phiA[wm2 + mi * 16 + fr][quad * 8];
      bf16x8 al = *(const bf16x8*)&phiA[wm2 + mi * 16 + fr][32 + quad * 8];
      acc[mi] = __builtin_amdgcn_mfma_f32_16x16x32_bf16(ah, bhf, acc[mi], 0, 0, 0);
      acc[mi] = __builtin_amdgcn_mfma_f32_16x16x32_bf16(ah, blf, acc[mi], 0, 0, 0);
      acc[mi] = __builtin_amdgcn_mfma_f32_16x16x32_bf16(al, bhf, acc[mi], 0, 0, 0);
    }
  }
  for (int f = tid; f < DEXP; f += 512) {
    float sum = 0.0f;
    if (f == 0) {
      sum = (float)CH;
    } else if (f < 17) {
      const float* p = kT[f - 1];
      for (int m = 0; m < CH; m += 4) {
        float4 x = *(const float4*)&p[m];
        sum += x.x + x.y + x.z + x.w;
      }
      sum *= 0.5f;
    } else {
      const float* pa2 = kT[(f - 17) >> 4];
      const float* pb2 = kT[(f - 17) & 15];
      for (int m = 0; m < CH; m += 4) {
        float4 x = *(const float4*)&pa2[m];
        float4 y = *(const float4*)&pb2[m];
        sum += x.x * y.x + x.y * y.y + x.z * y.z + x.w * y.w;
      }
      sum *= C2f;
    }
    csk[(size_t)blk * DEXP + f] = sum;
  }
  // ---- packed epilogue: LDS-transpose per slab (swizzled), then coalesced 16B stream ----
  __syncthreads();  // last MFMA reads of phiA/Vt done before reuse
  ushortT* stage = &phiA[0][0];  // 8KB staging
  ushortT* Sp = Spk + (size_t)blk * SPK_BLK_US;
#pragma unroll 1
  for (int sl = 0; sl < 9; sl++) {
    if (sl) __syncthreads();
#pragma unroll
    for (int mi = 0; mi < 9; mi++) {
      const int fb = wm2 + mi * 16;
      if ((fb >> 5) == sl) {  // wave-uniform
        const int fi0 = (fb & 31) + quad * 4;   // 0..28, mult of 4
        const int gh = fi0 >> 3;                // hi granule 0..3
        const int inner = (fi0 << 1) & 15;      // 0 or 8
        const int e = wn2 + fr;
        const int es = (e & 7) << 4;
        ushortT hh2[4], ll2[4];
#pragma unroll
        for (int r = 0; r < 4; r++) split_bf16(acc[mi][r], hh2[r], ll2[r]);
        char* rowp = (char*)stage + e * 128;
        *(ushort4*)(rowp + ((gh << 4) ^ es) + inner) = *(ushort4*)hh2;
        *(ushort4*)(rowp + (((gh + 4) << 4) ^ es) + inner) = *(ushort4*)ll2;
      }
    }
    __syncthreads();
    uint4* gdst = (uint4*)(Sp + (size_t)sl * SLAB_US);
    const uint4* lsrc = (const uint4*)stage;
    gdst[tid] = lsrc[tid];  // 512 uint4 = 8KB, one per thread
  }
}

// ---------------- K3: across-chunk scan (in place on packed Spk; csk f32) ----------------
__global__ __launch_bounds__(256) void prefix_kernel(ushortT* __restrict__ Spk,
                                                     float* __restrict__ csk) {
  const int gid = blockIdx.x * 256 + threadIdx.x;
  const int totS = NBH * 4608;  // per bh: 9 slab * 64 e * 8 word-pairs
  if (gid < totS) {
    const int bh = gid / 4608;
    const int rem = gid % 4608;
    const int slab = rem >> 9;
    const int e = (rem >> 3) & 63;
    const int wp = rem & 7;
    const int es = (e & 7) << 4;
    const unsigned off_h = e * 128 + ((((wp >> 1)) << 4) ^ es) + ((wp & 1) << 3);
    const unsigned off_l = e * 128 + ((((wp >> 1) + 4) << 4) ^ es) + ((wp & 1) << 3);
    char* base = (char*)Spk + (size_t)bh * NC * SPK_BLK_B + slab * 8192;
    float r0[NC], r1[NC], r2[NC], r3[NC];
    float t0 = 0.f, t1 = 0.f, t2 = 0.f, t3 = 0.f;
#pragma unroll
    for (int cc = 0; cc < NC; cc++) {
      const char* p = base + (size_t)cc * SPK_BLK_B;
      ushort4 hw = *(const ushort4*)(p + off_h);
      ushort4 lw = *(const ushort4*)(p + off_l);
      r0[cc] = __uint_as_float((unsigned)hw.x << 16) + __uint_as_float((unsigned)lw.x << 16);
      r1[cc] = __uint_as_float((unsigned)hw.y << 16) + __uint_as_float((unsigned)lw.y << 16);
      r2[cc] = __uint_as_float((unsigned)hw.z << 16) + __uint_as_float((unsigned)lw.z << 16);
      r3[cc] = __uint_as_float((unsigned)hw.w << 16) + __uint_as_float((unsigned)lw.w << 16);
      t0 += r0[cc]; t1 += r1[cc]; t2 += r2[cc]; t3 += r3[cc];
    }
    float u0 = 0.f, u1 = 0.f, u2 = 0.f, u3 = 0.f;
#pragma unroll
    for (int cc = 0; cc < NC; cc++) {
      ushort4 hw, lw;
      split_bf16(u0 + t0, hw.x, lw.x);
      split_bf16(u1 + t1, hw.y, lw.y);
      split_bf16(u2 + t2, hw.z, lw.z);
      split_bf16(u3 + t3, hw.w, lw.w);
      char* p = base + (size_t)cc * SPK_BLK_B;
      *(ushort4*)(p + off_h) = hw;
      *(ushort4*)(p + off_l) = lw;
      u0 += r0[cc]; u1 += r1[cc]; u2 += r2[cc]; u3 += r3[cc];
    }
  } else {
    const int g2 = gid - totS;
    if (g2 < NBH * DEXP) {
      const int bh = g2 / DEXP;
      const int f = g2 % DEXP;
      float r[NC];
      float tot = 0.0f;
#pragma unroll
      for (int cc = 0; cc < NC; cc++) {
        r[cc] = csk[(size_t)(bh * NC + cc) * DEXP + f];
        tot += r[cc];
      }
      float run = 0.0f;
#pragma unroll
      for (int cc = 0; cc < NC; cc++) {
        csk[(size_t)(bh * NC + cc) * DEXP + f] = run + tot;
        run += r[cc];
      }
    }
  }
}

// ---------------- fused_out: y = [phi(q)@G + P@V] / d, packed to Ahat ----------
// R2/R6-best structure (49.5 µs plateau across 7 variants — closed): 512 thr / 8
// waves, dbuf G-slab prefetch, denominator in MFMA via gk strip + zero-row B-tiles.
__global__ __launch_bounds__(512, 4) void fused_out(
    const float* __restrict__ qkv, const ushortT* __restrict__ Spk,
    const float* __restrict__ csk, ushortT* __restrict__ Ahat) {
  const int blk = blockIdx.x;
  const int bh = blk >> 4, c = blk & 15;
  const int b = bh / HH, h = bh % HH;
  __shared__ ushortT phiA[128][72];  // G-phase: phi(q) A-panel; PV-phase: P A-panel
  __shared__ ushortT GtD[2][4096];   // G-phase: dbuf packed G slab; PV: V^T overlay
  __shared__ ushortT qA1[128][24];   // qhi (K=16 data; K=32 dup synthesized at read)
  __shared__ ushortT qA2[128][24];   // qlo
  __shared__ ushortT kB[32][40];     // [khi|klo] per m-slab
  __shared__ ushortT gkS[9][64];     // per-slab gk strip: [hi(32)|lo(32)]
  __shared__ ushortT zero64[64];     // shared zero B-row
  __shared__ ushortT onesRow[64];    // PV ones B-row: hi=1.0 x32, lo=0
  __shared__ float zl[128];
  const int tid = threadIdx.x;
  const int wv = tid >> 6, lane = tid & 63;
  const int fr = lane & 15, quad = lane >> 4;
  const int prow = tid >> 2, pq = tid & 3;  // 4 threads per row, 8 features each
  const float* base = qkv + (size_t)(b * LL + c * CH) * 1152;
  const float* qrow = base + (size_t)prow * 1152 + h * 16;
  const ushortT* Gp = Spk + (size_t)blk * SPK_BLK_US;
  float qr[16];
#pragma unroll
  for (int i = 0; i < 4; i++) {
    float4 v = *(const float4*)(qrow + i * 4);
    qr[i * 4 + 0] = v.x; qr[i * 4 + 1] = v.y;
    qr[i * 4 + 2] = v.z; qr[i * 4 + 3] = v.w;
  }
  // prefetch slab 0: each wave stages 1KB
  gload_lds16(Gp + wv * 512 + lane * 8, &GtD[0][wv * 512]);
  // qA panels: each thread splits+writes its 4 q-values per panel
  {
    ushortT qh4[4], ql4[4];
#pragma unroll
    for (int i = 0; i < 4; i++) split_bf16(qr[pq * 4 + i], qh4[i], ql4[i]);
    *(ushort4*)&qA1[prow][pq * 4] = *(ushort4*)qh4;
    *(ushort4*)&qA2[prow][pq * 4] = *(ushort4*)ql4;
  }
  // gk strips (scanned inter-chunk k-state) -> LDS, split-bf16
  {
    const float* gkp = csk + (size_t)blk * DEXP;
    for (int f = tid; f < 288; f += 512) {
      float v = (f < DEXP) ? gkp[f] : 0.0f;
      ushortT hh, ll;
      split_bf16(v, hh, ll);
      gkS[f >> 5][f & 31] = hh;
      gkS[f >> 5][32 + (f & 31)] = ll;
    }
  }
  if (tid < 64) {
    zero64[tid] = 0;
    onesRow[tid] = (tid < 32) ? (ushortT)0x3F80 : (ushortT)0;
  }
  f32x4 acc[5] = {};
  // ---------------- G-phase ----------------
#pragma unroll 1
  for (int s = 0; s < 9; s++) {
    __syncthreads();  // slab-s data landed (own vmcnt(0)); prior-buffer reads done
    if (s < 8)
      gload_lds16(Gp + (s + 1) * SLAB_US + wv * 512 + lane * 8,
                  &GtD[(s + 1) & 1][wv * 512]);
    const int f0 = s * 32;
    // stage phi(q) A-panel: 8 features per thread (wave-private rows)
    {
      ushortT h8[8], l8[8];
#pragma unroll
      for (int j = 0; j < 8; j++) {
        const int f = f0 + pq * 8 + j;
        float v;
        if (f == 0) v = 1.0f;
        else if (f < 17) v = 0.5f * qr[f - 1];
        else if (f < DEXP) {
          const int ii = f - 17;
          v = C2f * qr[ii >> 4] * qr[ii & 15];
        } else v = 0.0f;
        split_bf16(v, h8[j], l8[j]);
      }
      *(uint4*)&phiA[prow][pq * 8] = *(uint4*)&h8[0];
      *(uint4*)&phiA[prow][32 + pq * 8] = *(uint4*)&l8[0];
    }
    // same-wave LDS write->read (wave-private rows), no barrier needed
    bf16x8 ah = *(const bf16x8*)&phiA[wv * 16 + fr][quad * 8];
    bf16x8 al = *(const bf16x8*)&phiA[wv * 16 + fr][32 + quad * 8];
    const char* gt = (const char*)&GtD[s & 1][0];
    const int sw = (fr & 7) << 4;  // e&7 == fr&7
#pragma unroll
    for (int ni = 0; ni < 4; ni++) {
      const int rb = (ni * 16 + fr) * 128;
      bf16x8 bh2 = *(const bf16x8*)(gt + rb + ((quad * 16) ^ sw));
      bf16x8 bl2 = *(const bf16x8*)(gt + rb + ((64 + quad * 16) ^ sw));
      acc[ni] = __builtin_amdgcn_mfma_f32_16x16x32_bf16(ah, bh2, acc[ni], 0, 0, 0);
      acc[ni] = __builtin_amdgcn_mfma_f32_16x16x32_bf16(ah, bl2, acc[ni], 0, 0, 0);
      acc[ni] = __builtin_amdgcn_mfma_f32_16x16x32_bf16(al, bh2, acc[ni], 0, 0, 0);
    }
    // denominator column: B col0 = gk strip, cols 1..15 = zero row (per-lane addr)
    {
      const ushortT* gp = (fr == 0) ? &gkS[s][0] : &zero64[0];
      bf16x8 gh = *(const bf16x8*)(gp + quad * 8);
      bf16x8 gl = *(const bf16x8*)(gp + 32 + quad * 8);
      acc[4] = __builtin_amdgcn_mfma_f32_16x16x32_bf16(ah, gh, acc[4], 0, 0, 0);
      acc[4] = __builtin_amdgcn_mfma_f32_16x16x32_bf16(ah, gl, acc[4], 0, 0, 0);
      acc[4] = __builtin_amdgcn_mfma_f32_16x16x32_bf16(al, gh, acc[4], 0, 0, 0);
    }
  }
  __syncthreads();  // G-phase GtD reads done before PV overlays it with V^T
  // ---------------- PV-phase (intra-chunk causal) ----------------
  ushortT* VtF = &GtD[0][0];  // V^T overlay: [64 e][72] rows, flat in GtD
#pragma unroll 1
  for (int s = 0; s < 4; s++) {
    const int m0 = s * 32;
    // stage kB = [khi|klo]
    if (tid < 128) {
      int mL = tid >> 2, i4 = (tid & 3) * 4;
      float4 k4 = *(const float4*)&base[(size_t)(m0 + mL) * 1152 + 192 + h * 16 + i4];
      ushortT hh[4], ll[4];
      split_bf16(k4.x, hh[0], ll[0]); split_bf16(k4.y, hh[1], ll[1]);
      split_bf16(k4.z, hh[2], ll[2]); split_bf16(k4.w, hh[3], ll[3]);
      *(ushort4*)&kB[mL][i4] = *(ushort4*)hh;
      *(ushort4*)&kB[mL][16 + i4] = *(ushort4*)ll;
    }
    // stage V^T slab into VtF
    {
      int mL = tid >> 4, e4 = (tid & 15) * 4;
      float4 v4 = *(const float4*)&base[(size_t)(m0 + mL) * 1152 + 384 + h * 64 + e4];
      ushortT hh[4], ll[4];
      split_bf16(v4.x, hh[0], ll[0]); split_bf16(v4.y, hh[1], ll[1]);
      split_bf16(v4.z, hh[2], ll[2]); split_bf16(v4.w, hh[3], ll[3]);
#pragma unroll
      for (int j = 0; j < 4; j++) {
        VtF[(e4 + j) * 72 + mL] = hh[j];
        VtF[(e4 + j) * 72 + 32 + mL] = ll[j];
      }
    }
    __syncthreads();
    if (s <= (wv >> 1)) {  // causal: slab contributes only to rows >= m0 (wave-uniform)
      // scores -> poly -> mask -> split -> scatter to phiA (wave-private rows)
      bf16x8 a1 = *(const bf16x8*)&qA1[wv * 16 + fr][(quad & 1) * 8];
      bf16x8 a2 = *(const bf16x8*)&qA2[wv * 16 + fr][(quad & 1) * 8];
#pragma unroll
      for (int mtt = 0; mtt < 2; mtt++) {
        bf16x8 bk = *(const bf16x8*)&kB[mtt * 16 + fr][quad * 8];
        f32x4 sf = {};
        sf = __builtin_amdgcn_mfma_f32_16x16x32_bf16(a1, bk, sf, 0, 0, 0);
        sf = __builtin_amdgcn_mfma_f32_16x16x32_bf16(a2, bk, sf, 0, 0, 0);
        const int mg = m0 + mtt * 16 + fr;
#pragma unroll
        for (int r = 0; r < 4; r++) {
          const int rowL = wv * 16 + quad * 4 + r;
          const float sv = sf[r];
          const float p = (mg <= rowL) ? fmaf(sv, fmaf(sv, 0.03125f, 0.25f), 1.0f) : 0.0f;
          ushortT ph, pl;
          split_bf16(p, ph, pl);
          phiA[rowL][mtt * 16 + fr] = ph;
          phiA[rowL][32 + mtt * 16 + fr] = pl;
        }
      }
      // P @ V (+ones col for rowsum) — same-wave LDS dependency, no barrier needed
      bf16x8 ah = *(const bf16x8*)&phiA[wv * 16 + fr][quad * 8];
      bf16x8 al = *(const bf16x8*)&phiA[wv * 16 + fr][32 + quad * 8];
#pragma unroll
      for (int ni = 0; ni < 4; ni++) {
        bf16x8 bh2 = *(const bf16x8*)&VtF[(ni * 16 + fr) * 72 + quad * 8];
        bf16x8 bl2 = *(const bf16x8*)&VtF[(ni * 16 + fr) * 72 + 32 + quad * 8];
        acc[ni] = __builtin_amdgcn_mfma_f32_16x16x32_bf16(ah, bh2, acc[ni], 0, 0, 0);
        acc[ni] = __builtin_amdgcn_mfma_f32_16x16x32_bf16(ah, bl2, acc[ni], 0, 0, 0);
        acc[ni] = __builtin_amdgcn_mfma_f32_16x16x32_bf16(al, bh2, acc[ni], 0, 0, 0);
      }
      {
        const ushortT* op = (fr == 0) ? &onesRow[0] : &zero64[0];
        bf16x8 oh = *(const bf16x8*)(op + quad * 8);
        acc[4] = __builtin_amdgcn_mfma_f32_16x16x32_bf16(ah, oh, acc[4], 0, 0, 0);
        acc[4] = __builtin_amdgcn_mfma_f32_16x16x32_bf16(al, oh, acc[4], 0, 0, 0);
      }
    }
    __syncthreads();
  }
  // ---------------- denominators + epilogue (all wave-private now) ----------------
  if (fr == 0) {
#pragma unroll
    for (int r = 0; r < 4; r++) {
      const int rowL = wv * 16 + quad * 4 + r;
      zl[rowL] = 1.0f / acc[4][r];
    }
  }
  const size_t rowbase = (size_t)(b * LL + c * CH);
#pragma unroll
  for (int ni = 0; ni < 4; ni++)
#pragma unroll
    for (int r = 0; r < 4; r++) {
      const int rowL = wv * 16 + quad * 4 + r;
      const float val = acc[ni][r] * zl[rowL];
      ushortT hh, ll;
      split_bf16(val, hh, ll);
      ushortT* ap = Ahat + (rowbase + rowL) * (size_t)KP + h * 64 + ni * 16 + fr;
      ap[0] = hh;
      ap[KH] = ll;
    }
}

extern "C" void kernel_launch(void* const* d_in, const int* in_sizes, int n_in,
                              void* d_out, int out_size, void* d_ws, size_t ws_size,
                              hipStream_t stream) {
  const float* hs = (const float*)d_in[0];
  const float* Wq = (const float*)d_in[1];
  const float* Wk = (const float*)d_in[2];
  const float* Wv = (const float*)d_in[3];
  const float* Wo = (const float*)d_in[4];
  float* out = (float*)d_out;
  char* ws = (char*)d_ws;
  // layout:
  float* qkv = (float*)(ws);                     // [0, 18874368)
  char*  attR = ws + 18874368;                   // [18874368, 31457280): What -> Ahat
  ushortT* Spk = (ushortT*)(ws + 31457280);      // [31457280, 59768832): packed G (28.3MB)
  float* csk = (float*)(ws + 59768832);          // 419328 -> end 60188160
  ushortT* Xhat = (ushortT*)(ws + 31457280);     // overlays Spk (dead before chunk_sum)
  ushortT* What = (ushortT*)attR;                // 1152*1536*2 = 3.5 MB (dead after QKV gemm)
  ushortT* Ahat = (ushortT*)attR;                // 4096*1536*2 = 12,582,912 (fits region)
  ushortT* Wohat = (ushortT*)qkv;                // 768*1536*2 (written after fused_out)
  const dim3 thr(256);
  // 1-2) pack inputs to [hi|lo] split-bf16
  pack_a<<<3072, thr, 0, stream>>>(hs, Xhat, 4096 * 192);
  pack_w<<<864, thr, 0, stream>>>(Wq, Wk, Wv, 192, 384, What, 1152 * 192);
  // 3) fused QKV projection -> qkv fp32 [4096][1152]  (512 thr, granule-major LDS)
  mfma_gemm<<<576, dim3(512), 0, stream>>>(Xhat, What, qkv, 1152, 18);
  // 4-5) per-chunk sums (packed/swizzled, 512 thr) + across-chunk scan in place
  chunk_sum_kernel<<<NBLK, dim3(512), 0, stream>>>(qkv, Spk, csk);
  {
    const int tot = NBH * 4608 + NBH * DEXP;
    prefix_kernel<<<(tot + 255) / 256, thr, 0, stream>>>(Spk, csk);
  }
  // 6) fused state + intra + scale + pack -> Ahat (512 thr / 8 waves)
  fused_out<<<NBLK, dim3(512), 0, stream>>>(qkv, Spk, csk, Ahat);
  // 7) pack Wo (qkv region dead now)
  pack_w<<<576, thr, 0, stream>>>(Wo, Wo, Wo, 768, 768, Wohat, 768 * 192);
  // 8) output projection (512 thr, granule-major LDS)
  mfma_gemm<<<384, dim3(512), 0, stream>>>(Ahat, Wohat, out, DM, 12);
}

// Round 13
// 227.610 us; speedup vs baseline: 1.1537x; 1.1537x over previous
//
#include <hip/hip_runtime.h>

typedef unsigned short ushortT;
typedef __bf16 bf16x8 __attribute__((ext_vector_type(8)));
typedef float f32x4 __attribute__((ext_vector_type(4)));

// Problem constants
#define BB   2
#define LL   2048
#define DM   768
#define HH   12
#define FT   16
#define HD   64
#define DEXP 273      // 1 + 16 + 256
#define CH   128      // chunk length
#define NC   16       // chunks per sequence (LL/CH)
#define NBH  24       // BB*HH
#define NBLK 384      // NBH*NC
#define C2f  0.17677669529663687f   // 1/(4*sqrt(2))
#define KH   768      // K per half
#define KP   1536     // packed row length: [hi(768) | lo(768)]
// packed-G geometry: per (bh,chunk): 9 slabs x [64 e][hi fi0..31 | lo fi0..31] ushorts,
// XOR-swizzled: 16B granule g within a 128B e-row lives at g^(e&7).
#define SLAB_US   4096     // ushorts per slab page (64*64)
#define SPK_BLK_US 36864   // 9 slabs
#define SPK_BLK_B  73728

// ---------------- split helpers ----------------
__device__ __forceinline__ void split_bf16(float x, ushortT& hi, ushortT& lo) {
  unsigned b = __float_as_uint(x);
  unsigned r = b + 0x7FFFu + ((b >> 16) & 1u);  // RNE to bf16
  hi = (ushortT)(r >> 16);
  float hf = __uint_as_float((unsigned)hi << 16);
  lo = (ushortT)(__float_as_uint(x - hf) >> 16);  // truncate
}

// X [M][768] f32 -> Xh [M][1536] bf16 = [hi | lo]
__global__ __launch_bounds__(256) void pack_a(const float* __restrict__ X,
                                              ushortT* __restrict__ Xh,
                                              int total4) {
  int g = blockIdx.x * 256 + threadIdx.x;
  if (g >= total4) return;
  int m = g / 192, k4 = (g % 192) * 4;
  float4 v = *(const float4*)(X + (size_t)m * 768 + k4);
  ushortT h[4], l[4];
  split_bf16(v.x, h[0], l[0]);
  split_bf16(v.y, h[1], l[1]);
  split_bf16(v.z, h[2], l[2]);
  split_bf16(v.w, h[3], l[3]);
  ushortT* p = Xh + (size_t)m * KP + k4;
  *(ushort4*)p = *(ushort4*)h;
  *(ushort4*)(p + KH) = *(ushort4*)l;
}

// W rows (selected from W0/W1/W2) -> Wh [N][1536] bf16 = [hi | lo]
__global__ __launch_bounds__(256) void pack_w(const float* __restrict__ W0,
                                              const float* __restrict__ W1,
                                              const float* __restrict__ W2,
                                              int n1, int n2,
                                              ushortT* __restrict__ Wh,
                                              int total4) {
  int g = blockIdx.x * 256 + threadIdx.x;
  if (g >= total4) return;
  int n = g / 192, k4 = (g % 192) * 4;
  const float* src = (n < n1 ? W0 + (size_t)n * 768
                    : n < n2 ? W1 + (size_t)(n - n1) * 768
                             : W2 + (size_t)(n - n2) * 768);
  float4 v = *(const float4*)(src + k4);
  ushortT h[4], l[4];
  split_bf16(v.x, h[0], l[0]);
  split_bf16(v.y, h[1], l[1]);
  split_bf16(v.z, h[2], l[2]);
  split_bf16(v.w, h[3], l[3]);
  ushortT* p = Wh + (size_t)n * KP + k4;
  *(ushort4*)p = *(ushort4*)h;
  *(ushort4*)(p + KH) = *(ushort4*)l;
}

// async global->LDS, 16B per lane; lds base must be wave-uniform (lane*16 implicit)
typedef const __attribute__((address_space(1))) unsigned gq_t;
typedef __attribute__((address_space(3))) unsigned lq_t;
__device__ __forceinline__ void gload_lds16(const ushortT* g, ushortT* l) {
  __builtin_amdgcn_global_load_lds((gq_t*)g, (lq_t*)l, 16, 0, 0);
}

// ---------------- MFMA GEMM: Y[M][N] = A[M][KP] @ B[N][KP]^T (3-term split-bf16) -------
// R9-best (locked): 512 threads / 8 waves, 128x64 tile, 2-phase dbuf. Each wave
// computes a 32x32 quadrant (acc[2][2]); staging split 8 ways, 64B-contiguous
// coalesced segments (4 lanes/row). Row-major LDS (measured conflict-free for b128).
__global__ __launch_bounds__(512, 4) void mfma_gemm(const ushortT* __restrict__ A,
                                                    const ushortT* __restrict__ B,
                                                    float* __restrict__ Y, int ldy,
                                                    int ntiles) {
  __shared__ ushortT sAh[2][128 * 32], sAl[2][128 * 32];
  __shared__ ushortT sBh[2][64 * 32], sBl[2][64 * 32];
  const int blk = blockIdx.x;
  const int xcd = blk & 7, slot = blk >> 3;
  const int mtp = gridDim.x / (8 * ntiles);
  const int mt = xcd * mtp + slot / ntiles;
  const int nt = slot % ntiles;
  const int bm = mt * 128, bn = nt * 64;
  const int tid = threadIdx.x, wave = tid >> 6, lane = tid & 63;
  const int srow = lane >> 2, schk = (lane & 3) * 8;
  const ushortT* gsrc;
  ushortT* lb0;
  ushortT* lb1;
  int iters;
  switch (wave) {
    case 0:  gsrc = A + (size_t)(bm + srow) * KP + schk;           lb0 = sAh[0];        lb1 = sAh[1];        iters = 4; break;
    case 1:  gsrc = A + (size_t)(bm + 64 + srow) * KP + schk;      lb0 = sAh[0] + 2048; lb1 = sAh[1] + 2048; iters = 4; break;
    case 2:  gsrc = A + (size_t)(bm + srow) * KP + KH + schk;      lb0 = sAl[0];        lb1 = sAl[1];        iters = 4; break;
    case 3:  gsrc = A + (size_t)(bm + 64 + srow) * KP + KH + schk; lb0 = sAl[0] + 2048; lb1 = sAl[1] + 2048; iters = 4; break;
    case 4:  gsrc = B + (size_t)(bn + srow) * KP + schk;           lb0 = sBh[0];        lb1 = sBh[1];        iters = 2; break;
    case 5:  gsrc = B + (size_t)(bn + 32 + srow) * KP + schk;      lb0 = sBh[0] + 1024; lb1 = sBh[1] + 1024; iters = 2; break;
    case 6:  gsrc = B + (size_t)(bn + srow) * KP + KH + schk;      lb0 = sBl[0];        lb1 = sBl[1];        iters = 2; break;
    default: gsrc = B + (size_t)(bn + 32 + srow) * KP + KH + schk; lb0 = sBl[0] + 1024; lb1 = sBl[1] + 1024; iters = 2; break;
  }
  const int wm = (wave >> 1) * 32, wn = (wave & 1) * 32;
  const int fr = lane & 15, quad = lane >> 4;
  f32x4 acc[2][2] = {};
  // prologue: stage K-step 0 into buffer 0
  for (int it = 0; it < iters; it++)
    gload_lds16(gsrc + (size_t)it * 16 * KP, lb0 + it * 512);
  __syncthreads();  // vmcnt(0) drain: step-0 tiles landed
#pragma unroll 2
  for (int step = 0; step < 24; step++) {
    const int cur = step & 1;
    // prefetch next K-step into the other buffer (in flight across compute)
    if (step < 23) {
      ushortT* lbn = cur ? lb0 : lb1;
      const int k1 = (step + 1) * 32;
      for (int it = 0; it < iters; it++)
        gload_lds16(gsrc + k1 + (size_t)it * 16 * KP, lbn + it * 512);
    }
    const ushortT* pAh = sAh[cur];
    const ushortT* pAl = sAl[cur];
    const ushortT* pBh = sBh[cur];
    const ushortT* pBl = sBl[cur];
    bf16x8 ah[2], al[2], bh2[2], bl2[2];
#pragma unroll
    for (int mi = 0; mi < 2; mi++) {
      ah[mi] = *(const bf16x8*)&pAh[(wm + mi * 16 + fr) * 32 + quad * 8];
      al[mi] = *(const bf16x8*)&pAl[(wm + mi * 16 + fr) * 32 + quad * 8];
    }
#pragma unroll
    for (int ni = 0; ni < 2; ni++) {
      bh2[ni] = *(const bf16x8*)&pBh[(wn + ni * 16 + fr) * 32 + quad * 8];
      bl2[ni] = *(const bf16x8*)&pBl[(wn + ni * 16 + fr) * 32 + quad * 8];
    }
#pragma unroll
    for (int mi = 0; mi < 2; mi++)
#pragma unroll
      for (int ni = 0; ni < 2; ni++) {
        acc[mi][ni] = __builtin_amdgcn_mfma_f32_16x16x32_bf16(ah[mi], bh2[ni], acc[mi][ni], 0, 0, 0);
        acc[mi][ni] = __builtin_amdgcn_mfma_f32_16x16x32_bf16(ah[mi], bl2[ni], acc[mi][ni], 0, 0, 0);
        acc[mi][ni] = __builtin_amdgcn_mfma_f32_16x16x32_bf16(al[mi], bh2[ni], acc[mi][ni], 0, 0, 0);
      }
    __syncthreads();  // drains vmcnt(0): next-step tiles landed; cur reads done
  }
  const int orow = quad * 4;
#pragma unroll
  for (int mi = 0; mi < 2; mi++)
#pragma unroll
    for (int ni = 0; ni < 2; ni++) {
      float* yp = Y + (size_t)(bm + wm + mi * 16 + orow) * ldy + bn + wn + ni * 16 + fr;
#pragma unroll
      for (int r = 0; r < 4; r++) yp[(size_t)r * ldy] = acc[mi][ni][r];
    }
}

// ---------------- K2: Spk = phi_k^T @ V via MFMA, written packed/transposed/swizzled ----
// R8: 512 threads / 8 waves. phi build split 2 threads/row (VALU halves); MFMA
// retiled 18 row-tiles x 4 col-tiles over 8 waves (9 tiles each, acc[9]).
__global__ __launch_bounds__(512, 4) void chunk_sum_kernel(
    const float* __restrict__ qkv, ushortT* __restrict__ Spk,
    float* __restrict__ csk) {
  const int blk = blockIdx.x;
  const int bh = blk >> 4, c = blk & 15;
  const int b = bh / HH, h = bh % HH;
  __shared__ float kT[16][128];
  __shared__ ushortT phiA[288][72];
  __shared__ ushortT Vt[64][72];
  const float* base = qkv + (size_t)(b * LL + c * CH) * 1152;
  const int tid = threadIdx.x;
  const int wave = tid >> 6, lane = tid & 63;
  const int fr = lane & 15, quad = lane >> 4;
  // kT load: one item per thread (512 items)
  {
    const int m = tid >> 2, i4 = (tid & 3) * 4;
    float4 k4 = *(const float4*)&base[(size_t)m * 1152 + 192 + h * 16 + i4];
    kT[i4 + 0][m] = k4.x; kT[i4 + 1][m] = k4.y;
    kT[i4 + 2][m] = k4.z; kT[i4 + 3][m] = k4.w;
  }
  const int wm2 = (wave & 1) * 144;   // row half: 9 tiles of 16
  const int wn2 = (wave >> 1) * 16;   // col tile: 16 e
  f32x4 acc[9] = {};
  __syncthreads();
#pragma unroll 1
  for (int s = 0; s < 4; s++) {
    const int m0 = s * 32;
    if (s) __syncthreads();
    // Vt stage: one item per thread (512 items)
    {
      const int m = m0 + (tid >> 4), e4 = (tid & 15) * 4;
      float4 v4 = *(const float4*)&base[(size_t)m * 1152 + 384 + h * 64 + e4];
      ushortT hh[4], ll[4];
      split_bf16(v4.x, hh[0], ll[0]); split_bf16(v4.y, hh[1], ll[1]);
      split_bf16(v4.z, hh[2], ll[2]); split_bf16(v4.w, hh[3], ll[3]);
      const int mi2 = m - m0;
#pragma unroll
      for (int j = 0; j < 4; j++) {
        Vt[e4 + j][mi2] = hh[j];
        Vt[e4 + j][32 + mi2] = ll[j];
      }
    }
    // phi build: 576 half-rows (2 threads per feature row, 16 m-values each)
    for (int idx = tid; idx < 576; idx += 512) {
      const int f = idx >> 1, hf = (idx & 1) * 16;
      const float* pa = (f >= 17) ? kT[(f - 17) >> 4] : (f >= 1 ? kT[f - 1] : kT[0]);
      const float* pb = (f >= 17) ? kT[(f - 17) & 15] : kT[0];
      const float sc = (f == 0) ? 1.0f : (f < 17 ? 0.5f : C2f);
      const bool quadf = (f >= 17);
      const bool valid = (f < DEXP);
      ushortT hrow[16], lrow[16];
#pragma unroll
      for (int g = 0; g < 4; g++) {
        float4 a4 = *(const float4*)&pa[m0 + hf + g * 4];
        float4 b4 = *(const float4*)&pb[m0 + hf + g * 4];
        float v0, v1, v2, v3;
        if (f == 0) {
          v0 = v1 = v2 = v3 = 1.0f;
        } else if (!quadf) {
          v0 = sc * a4.x; v1 = sc * a4.y; v2 = sc * a4.z; v3 = sc * a4.w;
        } else {
          v0 = sc * a4.x * b4.x; v1 = sc * a4.y * b4.y;
          v2 = sc * a4.z * b4.z; v3 = sc * a4.w * b4.w;
        }
        if (!valid) { v0 = v1 = v2 = v3 = 0.0f; }
        split_bf16(v0, hrow[g * 4 + 0], lrow[g * 4 + 0]);
        split_bf16(v1, hrow[g * 4 + 1], lrow[g * 4 + 1]);
        split_bf16(v2, hrow[g * 4 + 2], lrow[g * 4 + 2]);
        split_bf16(v3, hrow[g * 4 + 3], lrow[g * 4 + 3]);
      }
      *(uint4*)&phiA[f][hf] = *(uint4*)&hrow[0];
      *(uint4*)&phiA[f][hf + 8] = *(uint4*)&hrow[8];
      *(uint4*)&phiA[f][32 + hf] = *(uint4*)&lrow[0];
      *(uint4*)&phiA[f][32 + hf + 8] = *(uint4*)&lrow[8];
    }
    __syncthreads();
    bf16x8 bhf = *(const bf16x8*)&Vt[wn2 + fr][quad * 8];
    bf16x8 blf = *(const bf16x8*)&Vt[wn2 + fr][32 + quad * 8];
#pragma unroll
    for (int mi = 0; mi < 9; mi++) {
      bf16x8 ah = *(const bf16x8*)&phiA[wm2 + mi * 16 + fr][quad * 8];
      bf16x8 al = *(const bf16x8*)&phiA[wm2 + mi * 16 + fr][32 + quad * 8];
      acc[mi] = __builtin_amdgcn_mfma_f32_16x16x32_bf16(ah, bhf, acc[mi], 0, 0, 0);
      acc[mi] = __builtin_amdgcn_mfma_f32_16x16x32_bf16(ah, blf, acc[mi], 0, 0, 0);
      acc[mi] = __builtin_amdgcn_mfma_f32_16x16x32_bf16(al, bhf, acc[mi], 0, 0, 0);
    }
  }
  for (int f = tid; f < DEXP; f += 512) {
    float sum = 0.0f;
    if (f == 0) {
      sum = (float)CH;
    } else if (f < 17) {
      const float* p = kT[f - 1];
      for (int m = 0; m < CH; m += 4) {
        float4 x = *(const float4*)&p[m];
        sum += x.x + x.y + x.z + x.w;
      }
      sum *= 0.5f;
    } else {
      const float* pa2 = kT[(f - 17) >> 4];
      const float* pb2 = kT[(f - 17) & 15];
      for (int m = 0; m < CH; m += 4) {
        float4 x = *(const float4*)&pa2[m];
        float4 y = *(const float4*)&pb2[m];
        sum += x.x * y.x + x.y * y.y + x.z * y.z + x.w * y.w;
      }
      sum *= C2f;
    }
    csk[(size_t)blk * DEXP + f] = sum;
  }
  // ---- packed epilogue: LDS-transpose per slab (swizzled), then coalesced 16B stream ----
  __syncthreads();  // last MFMA reads of phiA/Vt done before reuse
  ushortT* stage = &phiA[0][0];  // 8KB staging
  ushortT* Sp = Spk + (size_t)blk * SPK_BLK_US;
#pragma unroll 1
  for (int sl = 0; sl < 9; sl++) {
    if (sl) __syncthreads();
#pragma unroll
    for (int mi = 0; mi < 9; mi++) {
      const int fb = wm2 + mi * 16;
      if ((fb >> 5) == sl) {  // wave-uniform
        const int fi0 = (fb & 31) + quad * 4;   // 0..28, mult of 4
        const int gh = fi0 >> 3;                // hi granule 0..3
        const int inner = (fi0 << 1) & 15;      // 0 or 8
        const int e = wn2 + fr;
        const int es = (e & 7) << 4;
        ushortT hh2[4], ll2[4];
#pragma unroll
        for (int r = 0; r < 4; r++) split_bf16(acc[mi][r], hh2[r], ll2[r]);
        char* rowp = (char*)stage + e * 128;
        *(ushort4*)(rowp + ((gh << 4) ^ es) + inner) = *(ushort4*)hh2;
        *(ushort4*)(rowp + (((gh + 4) << 4) ^ es) + inner) = *(ushort4*)ll2;
      }
    }
    __syncthreads();
    uint4* gdst = (uint4*)(Sp + (size_t)sl * SLAB_US);
    const uint4* lsrc = (const uint4*)stage;
    gdst[tid] = lsrc[tid];  // 512 uint4 = 8KB, one per thread
  }
}

// ---------------- K3: across-chunk scan (in place on packed Spk; csk f32) ----------------
__global__ __launch_bounds__(256) void prefix_kernel(ushortT* __restrict__ Spk,
                                                     float* __restrict__ csk) {
  const int gid = blockIdx.x * 256 + threadIdx.x;
  const int totS = NBH * 4608;  // per bh: 9 slab * 64 e * 8 word-pairs
  if (gid < totS) {
    const int bh = gid / 4608;
    const int rem = gid % 4608;
    const int slab = rem >> 9;
    const int e = (rem >> 3) & 63;
    const int wp = rem & 7;
    const int es = (e & 7) << 4;
    const unsigned off_h = e * 128 + ((((wp >> 1)) << 4) ^ es) + ((wp & 1) << 3);
    const unsigned off_l = e * 128 + ((((wp >> 1) + 4) << 4) ^ es) + ((wp & 1) << 3);
    char* base = (char*)Spk + (size_t)bh * NC * SPK_BLK_B + slab * 8192;
    float r0[NC], r1[NC], r2[NC], r3[NC];
    float t0 = 0.f, t1 = 0.f, t2 = 0.f, t3 = 0.f;
#pragma unroll
    for (int cc = 0; cc < NC; cc++) {
      const char* p = base + (size_t)cc * SPK_BLK_B;
      ushort4 hw = *(const ushort4*)(p + off_h);
      ushort4 lw = *(const ushort4*)(p + off_l);
      r0[cc] = __uint_as_float((unsigned)hw.x << 16) + __uint_as_float((unsigned)lw.x << 16);
      r1[cc] = __uint_as_float((unsigned)hw.y << 16) + __uint_as_float((unsigned)lw.y << 16);
      r2[cc] = __uint_as_float((unsigned)hw.z << 16) + __uint_as_float((unsigned)lw.z << 16);
      r3[cc] = __uint_as_float((unsigned)hw.w << 16) + __uint_as_float((unsigned)lw.w << 16);
      t0 += r0[cc]; t1 += r1[cc]; t2 += r2[cc]; t3 += r3[cc];
    }
    float u0 = 0.f, u1 = 0.f, u2 = 0.f, u3 = 0.f;
#pragma unroll
    for (int cc = 0; cc < NC; cc++) {
      ushort4 hw, lw;
      split_bf16(u0 + t0, hw.x, lw.x);
      split_bf16(u1 + t1, hw.y, lw.y);
      split_bf16(u2 + t2, hw.z, lw.z);
      split_bf16(u3 + t3, hw.w, lw.w);
      char* p = base + (size_t)cc * SPK_BLK_B;
      *(ushort4*)(p + off_h) = hw;
      *(ushort4*)(p + off_l) = lw;
      u0 += r0[cc]; u1 += r1[cc]; u2 += r2[cc]; u3 += r3[cc];
    }
  } else {
    const int g2 = gid - totS;
    if (g2 < NBH * DEXP) {
      const int bh = g2 / DEXP;
      const int f = g2 % DEXP;
      float r[NC];
      float tot = 0.0f;
#pragma unroll
      for (int cc = 0; cc < NC; cc++) {
        r[cc] = csk[(size_t)(bh * NC + cc) * DEXP + f];
        tot += r[cc];
      }
      float run = 0.0f;
#pragma unroll
      for (int cc = 0; cc < NC; cc++) {
        csk[(size_t)(bh * NC + cc) * DEXP + f] = run + tot;
        run += r[cc];
      }
    }
  }
}

// ---------------- fused_out: y = [phi(q)@G + P@V] / d, packed to Ahat ----------
// R2/R6-best structure (49.5 µs plateau across 7 variants — closed): 512 thr / 8
// waves, dbuf G-slab prefetch, denominator in MFMA via gk strip + zero-row B-tiles.
__global__ __launch_bounds__(512, 4) void fused_out(
    const float* __restrict__ qkv, const ushortT* __restrict__ Spk,
    const float* __restrict__ csk, ushortT* __restrict__ Ahat) {
  const int blk = blockIdx.x;
  const int bh = blk >> 4, c = blk & 15;
  const int b = bh / HH, h = bh % HH;
  __shared__ ushortT phiA[128][72];  // G-phase: phi(q) A-panel; PV-phase: P A-panel
  __shared__ ushortT GtD[2][4096];   // G-phase: dbuf packed G slab; PV: V^T overlay
  __shared__ ushortT qA1[128][24];   // qhi (K=16 data; K=32 dup synthesized at read)
  __shared__ ushortT qA2[128][24];   // qlo
  __shared__ ushortT kB[32][40];     // [khi|klo] per m-slab
  __shared__ ushortT gkS[9][64];     // per-slab gk strip: [hi(32)|lo(32)]
  __shared__ ushortT zero64[64];     // shared zero B-row
  __shared__ ushortT onesRow[64];    // PV ones B-row: hi=1.0 x32, lo=0
  __shared__ float zl[128];
  const int tid = threadIdx.x;
  const int wv = tid >> 6, lane = tid & 63;
  const int fr = lane & 15, quad = lane >> 4;
  const int prow = tid >> 2, pq = tid & 3;  // 4 threads per row, 8 features each
  const float* base = qkv + (size_t)(b * LL + c * CH) * 1152;
  const float* qrow = base + (size_t)prow * 1152 + h * 16;
  const ushortT* Gp = Spk + (size_t)blk * SPK_BLK_US;
  float qr[16];
#pragma unroll
  for (int i = 0; i < 4; i++) {
    float4 v = *(const float4*)(qrow + i * 4);
    qr[i * 4 + 0] = v.x; qr[i * 4 + 1] = v.y;
    qr[i * 4 + 2] = v.z; qr[i * 4 + 3] = v.w;
  }
  // prefetch slab 0: each wave stages 1KB
  gload_lds16(Gp + wv * 512 + lane * 8, &GtD[0][wv * 512]);
  // qA panels: each thread splits+writes its 4 q-values per panel
  {
    ushortT qh4[4], ql4[4];
#pragma unroll
    for (int i = 0; i < 4; i++) split_bf16(qr[pq * 4 + i], qh4[i], ql4[i]);
    *(ushort4*)&qA1[prow][pq * 4] = *(ushort4*)qh4;
    *(ushort4*)&qA2[prow][pq * 4] = *(ushort4*)ql4;
  }
  // gk strips (scanned inter-chunk k-state) -> LDS, split-bf16
  {
    const float* gkp = csk + (size_t)blk * DEXP;
    for (int f = tid; f < 288; f += 512) {
      float v = (f < DEXP) ? gkp[f] : 0.0f;
      ushortT hh, ll;
      split_bf16(v, hh, ll);
      gkS[f >> 5][f & 31] = hh;
      gkS[f >> 5][32 + (f & 31)] = ll;
    }
  }
  if (tid < 64) {
    zero64[tid] = 0;
    onesRow[tid] = (tid < 32) ? (ushortT)0x3F80 : (ushortT)0;
  }
  f32x4 acc[5] = {};
  // ---------------- G-phase ----------------
#pragma unroll 1
  for (int s = 0; s < 9; s++) {
    __syncthreads();  // slab-s data landed (own vmcnt(0)); prior-buffer reads done
    if (s < 8)
      gload_lds16(Gp + (s + 1) * SLAB_US + wv * 512 + lane * 8,
                  &GtD[(s + 1) & 1][wv * 512]);
    const int f0 = s * 32;
    // stage phi(q) A-panel: 8 features per thread (wave-private rows)
    {
      ushortT h8[8], l8[8];
#pragma unroll
      for (int j = 0; j < 8; j++) {
        const int f = f0 + pq * 8 + j;
        float v;
        if (f == 0) v = 1.0f;
        else if (f < 17) v = 0.5f * qr[f - 1];
        else if (f < DEXP) {
          const int ii = f - 17;
          v = C2f * qr[ii >> 4] * qr[ii & 15];
        } else v = 0.0f;
        split_bf16(v, h8[j], l8[j]);
      }
      *(uint4*)&phiA[prow][pq * 8] = *(uint4*)&h8[0];
      *(uint4*)&phiA[prow][32 + pq * 8] = *(uint4*)&l8[0];
    }
    // same-wave LDS write->read (wave-private rows), no barrier needed
    bf16x8 ah = *(const bf16x8*)&phiA[wv * 16 + fr][quad * 8];
    bf16x8 al = *(const bf16x8*)&phiA[wv * 16 + fr][32 + quad * 8];
    const char* gt = (const char*)&GtD[s & 1][0];
    const int sw = (fr & 7) << 4;  // e&7 == fr&7
#pragma unroll
    for (int ni = 0; ni < 4; ni++) {
      const int rb = (ni * 16 + fr) * 128;
      bf16x8 bh2 = *(const bf16x8*)(gt + rb + ((quad * 16) ^ sw));
      bf16x8 bl2 = *(const bf16x8*)(gt + rb + ((64 + quad * 16) ^ sw));
      acc[ni] = __builtin_amdgcn_mfma_f32_16x16x32_bf16(ah, bh2, acc[ni], 0, 0, 0);
      acc[ni] = __builtin_amdgcn_mfma_f32_16x16x32_bf16(ah, bl2, acc[ni], 0, 0, 0);
      acc[ni] = __builtin_amdgcn_mfma_f32_16x16x32_bf16(al, bh2, acc[ni], 0, 0, 0);
    }
    // denominator column: B col0 = gk strip, cols 1..15 = zero row (per-lane addr)
    {
      const ushortT* gp = (fr == 0) ? &gkS[s][0] : &zero64[0];
      bf16x8 gh = *(const bf16x8*)(gp + quad * 8);
      bf16x8 gl = *(const bf16x8*)(gp + 32 + quad * 8);
      acc[4] = __builtin_amdgcn_mfma_f32_16x16x32_bf16(ah, gh, acc[4], 0, 0, 0);
      acc[4] = __builtin_amdgcn_mfma_f32_16x16x32_bf16(ah, gl, acc[4], 0, 0, 0);
      acc[4] = __builtin_amdgcn_mfma_f32_16x16x32_bf16(al, gh, acc[4], 0, 0, 0);
    }
  }
  __syncthreads();  // G-phase GtD reads done before PV overlays it with V^T
  // ---------------- PV-phase (intra-chunk causal) ----------------
  ushortT* VtF = &GtD[0][0];  // V^T overlay: [64 e][72] rows, flat in GtD
#pragma unroll 1
  for (int s = 0; s < 4; s++) {
    const int m0 = s * 32;
    // stage kB = [khi|klo]
    if (tid < 128) {
      int mL = tid >> 2, i4 = (tid & 3) * 4;
      float4 k4 = *(const float4*)&base[(size_t)(m0 + mL) * 1152 + 192 + h * 16 + i4];
      ushortT hh[4], ll[4];
      split_bf16(k4.x, hh[0], ll[0]); split_bf16(k4.y, hh[1], ll[1]);
      split_bf16(k4.z, hh[2], ll[2]); split_bf16(k4.w, hh[3], ll[3]);
      *(ushort4*)&kB[mL][i4] = *(ushort4*)hh;
      *(ushort4*)&kB[mL][16 + i4] = *(ushort4*)ll;
    }
    // stage V^T slab into VtF
    {
      int mL = tid >> 4, e4 = (tid & 15) * 4;
      float4 v4 = *(const float4*)&base[(size_t)(m0 + mL) * 1152 + 384 + h * 64 + e4];
      ushortT hh[4], ll[4];
      split_bf16(v4.x, hh[0], ll[0]); split_bf16(v4.y, hh[1], ll[1]);
      split_bf16(v4.z, hh[2], ll[2]); split_bf16(v4.w, hh[3], ll[3]);
#pragma unroll
      for (int j = 0; j < 4; j++) {
        VtF[(e4 + j) * 72 + mL] = hh[j];
        VtF[(e4 + j) * 72 + 32 + mL] = ll[j];
      }
    }
    __syncthreads();
    if (s <= (wv >> 1)) {  // causal: slab contributes only to rows >= m0 (wave-uniform)
      // scores -> poly -> mask -> split -> scatter to phiA (wave-private rows)
      bf16x8 a1 = *(const bf16x8*)&qA1[wv * 16 + fr][(quad & 1) * 8];
      bf16x8 a2 = *(const bf16x8*)&qA2[wv * 16 + fr][(quad & 1) * 8];
#pragma unroll
      for (int mtt = 0; mtt < 2; mtt++) {
        bf16x8 bk = *(const bf16x8*)&kB[mtt * 16 + fr][quad * 8];
        f32x4 sf = {};
        sf = __builtin_amdgcn_mfma_f32_16x16x32_bf16(a1, bk, sf, 0, 0, 0);
        sf = __builtin_amdgcn_mfma_f32_16x16x32_bf16(a2, bk, sf, 0, 0, 0);
        const int mg = m0 + mtt * 16 + fr;
#pragma unroll
        for (int r = 0; r < 4; r++) {
          const int rowL = wv * 16 + quad * 4 + r;
          const float sv = sf[r];
          const float p = (mg <= rowL) ? fmaf(sv, fmaf(sv, 0.03125f, 0.25f), 1.0f) : 0.0f;
          ushortT ph, pl;
          split_bf16(p, ph, pl);
          phiA[rowL][mtt * 16 + fr] = ph;
          phiA[rowL][32 + mtt * 16 + fr] = pl;
        }
      }
      // P @ V (+ones col for rowsum) — same-wave LDS dependency, no barrier needed
      bf16x8 ah = *(const bf16x8*)&phiA[wv * 16 + fr][quad * 8];
      bf16x8 al = *(const bf16x8*)&phiA[wv * 16 + fr][32 + quad * 8];
#pragma unroll
      for (int ni = 0; ni < 4; ni++) {
        bf16x8 bh2 = *(const bf16x8*)&VtF[(ni * 16 + fr) * 72 + quad * 8];
        bf16x8 bl2 = *(const bf16x8*)&VtF[(ni * 16 + fr) * 72 + 32 + quad * 8];
        acc[ni] = __builtin_amdgcn_mfma_f32_16x16x32_bf16(ah, bh2, acc[ni], 0, 0, 0);
        acc[ni] = __builtin_amdgcn_mfma_f32_16x16x32_bf16(ah, bl2, acc[ni], 0, 0, 0);
        acc[ni] = __builtin_amdgcn_mfma_f32_16x16x32_bf16(al, bh2, acc[ni], 0, 0, 0);
      }
      {
        const ushortT* op = (fr == 0) ? &onesRow[0] : &zero64[0];
        bf16x8 oh = *(const bf16x8*)(op + quad * 8);
        acc[4] = __builtin_amdgcn_mfma_f32_16x16x32_bf16(ah, oh, acc[4], 0, 0, 0);
        acc[4] = __builtin_amdgcn_mfma_f32_16x16x32_bf16(al, oh, acc[4], 0, 0, 0);
      }
    }
    __syncthreads();
  }
  // ---------------- denominators + epilogue (all wave-private now) ----------------
  if (fr == 0) {
#pragma unroll
    for (int r = 0; r < 4; r++) {
      const int rowL = wv * 16 + quad * 4 + r;
      zl[rowL] = 1.0f / acc[4][r];
    }
  }
  const size_t rowbase = (size_t)(b * LL + c * CH);
#pragma unroll
  for (int ni = 0; ni < 4; ni++)
#pragma unroll
    for (int r = 0; r < 4; r++) {
      const int rowL = wv * 16 + quad * 4 + r;
      const float val = acc[ni][r] * zl[rowL];
      ushortT hh, ll;
      split_bf16(val, hh, ll);
      ushortT* ap = Ahat + (rowbase + rowL) * (size_t)KP + h * 64 + ni * 16 + fr;
      ap[0] = hh;
      ap[KH] = ll;
    }
}

extern "C" void kernel_launch(void* const* d_in, const int* in_sizes, int n_in,
                              void* d_out, int out_size, void* d_ws, size_t ws_size,
                              hipStream_t stream) {
  const float* hs = (const float*)d_in[0];
  const float* Wq = (const float*)d_in[1];
  const float* Wk = (const float*)d_in[2];
  const float* Wv = (const float*)d_in[3];
  const float* Wo = (const float*)d_in[4];
  float* out = (float*)d_out;
  char* ws = (char*)d_ws;
  // layout:
  float* qkv = (float*)(ws);                     // [0, 18874368)
  char*  attR = ws + 18874368;                   // [18874368, 31457280): What -> Ahat
  ushortT* Spk = (ushortT*)(ws + 31457280);      // [31457280, 59768832): packed G (28.3MB)
  float* csk = (float*)(ws + 59768832);          // 419328 -> end 60188160
  ushortT* Xhat = (ushortT*)(ws + 31457280);     // overlays Spk (dead before chunk_sum)
  ushortT* What = (ushortT*)attR;                // 1152*1536*2 = 3.5 MB (dead after QKV gemm)
  ushortT* Ahat = (ushortT*)attR;                // 4096*1536*2 = 12,582,912 (fits region)
  ushortT* Wohat = (ushortT*)qkv;                // 768*1536*2 (written after fused_out)
  const dim3 thr(256);
  // 1-2) pack inputs to [hi|lo] split-bf16
  pack_a<<<3072, thr, 0, stream>>>(hs, Xhat, 4096 * 192);
  pack_w<<<864, thr, 0, stream>>>(Wq, Wk, Wv, 192, 384, What, 1152 * 192);
  // 3) fused QKV projection -> qkv fp32 [4096][1152]  (512 thr / 8 waves)
  mfma_gemm<<<576, dim3(512), 0, stream>>>(Xhat, What, qkv, 1152, 18);
  // 4-5) per-chunk sums (packed/swizzled, 512 thr) + across-chunk scan in place
  chunk_sum_kernel<<<NBLK, dim3(512), 0, stream>>>(qkv, Spk, csk);
  {
    const int tot = NBH * 4608 + NBH * DEXP;
    prefix_kernel<<<(tot + 255) / 256, thr, 0, stream>>>(Spk, csk);
  }
  // 6) fused state + intra + scale + pack -> Ahat (512 thr / 8 waves)
  fused_out<<<NBLK, dim3(512), 0, stream>>>(qkv, Spk, csk, Ahat);
  // 7) pack Wo (qkv region dead now)
  pack_w<<<576, thr, 0, stream>>>(Wo, Wo, Wo, 768, 768, Wohat, 768 * 192);
  // 8) output projection (512 thr / 8 waves)
  mfma_gemm<<<384, dim3(512), 0, stream>>>(Ahat, Wohat, out, DM, 12);
}

// Round 14
// 225.616 us; speedup vs baseline: 1.1639x; 1.0088x over previous
//
#include <hip/hip_runtime.h>

typedef unsigned short ushortT;
typedef __bf16 bf16x8 __attribute__((ext_vector_type(8)));
typedef float f32x4 __attribute__((ext_vector_type(4)));

// Problem constants
#define BB   2
#define LL   2048
#define DM   768
#define HH   12
#define FT   16
#define HD   64
#define DEXP 273      // 1 + 16 + 256
#define CH   128      // chunk length
#define NC   16       // chunks per sequence (LL/CH)
#define NBH  24       // BB*HH
#define NBLK 384      // NBH*NC
#define C2f  0.17677669529663687f   // 1/(4*sqrt(2))
#define KH   768      // K per half
#define KP   1536     // packed row length: [hi(768) | lo(768)]
// packed-G geometry: per (bh,chunk): 9 slabs x [64 e][hi fi0..31 | lo fi0..31] ushorts,
// XOR-swizzled: 16B granule g within a 128B e-row lives at g^(e&7).
#define SLAB_US   4096     // ushorts per slab page (64*64)
#define SPK_BLK_US 36864   // 9 slabs
#define SPK_BLK_B  73728

// ---------------- split helpers ----------------
__device__ __forceinline__ void split_bf16(float x, ushortT& hi, ushortT& lo) {
  unsigned b = __float_as_uint(x);
  unsigned r = b + 0x7FFFu + ((b >> 16) & 1u);  // RNE to bf16
  hi = (ushortT)(r >> 16);
  float hf = __uint_as_float((unsigned)hi << 16);
  lo = (ushortT)(__float_as_uint(x - hf) >> 16);  // truncate
}

// Merged input pack: blocks [0,3072) pack X (hidden states) -> Xhat;
// blocks [3072,3936) pack Wq/Wk/Wv rows -> What. One launch instead of two.
__global__ __launch_bounds__(256) void pack_in(const float* __restrict__ X,
                                               ushortT* __restrict__ Xh,
                                               const float* __restrict__ W0,
                                               const float* __restrict__ W1,
                                               const float* __restrict__ W2,
                                               ushortT* __restrict__ Wh) {
  const int blk = blockIdx.x;
  if (blk < 3072) {
    int g = blk * 256 + threadIdx.x;
    if (g >= 4096 * 192) return;
    int m = g / 192, k4 = (g % 192) * 4;
    float4 v = *(const float4*)(X + (size_t)m * 768 + k4);
    ushortT h[4], l[4];
    split_bf16(v.x, h[0], l[0]);
    split_bf16(v.y, h[1], l[1]);
    split_bf16(v.z, h[2], l[2]);
    split_bf16(v.w, h[3], l[3]);
    ushortT* p = Xh + (size_t)m * KP + k4;
    *(ushort4*)p = *(ushort4*)h;
    *(ushort4*)(p + KH) = *(ushort4*)l;
  } else {
    int g = (blk - 3072) * 256 + threadIdx.x;
    if (g >= 1152 * 192) return;
    int n = g / 192, k4 = (g % 192) * 4;
    const float* src = (n < 192 ? W0 + (size_t)n * 768
                      : n < 384 ? W1 + (size_t)(n - 192) * 768
                                : W2 + (size_t)(n - 384) * 768);
    float4 v = *(const float4*)(src + k4);
    ushortT h[4], l[4];
    split_bf16(v.x, h[0], l[0]);
    split_bf16(v.y, h[1], l[1]);
    split_bf16(v.z, h[2], l[2]);
    split_bf16(v.w, h[3], l[3]);
    ushortT* p = Wh + (size_t)n * KP + k4;
    *(ushort4*)p = *(ushort4*)h;
    *(ushort4*)(p + KH) = *(ushort4*)l;
  }
}

// W rows (selected from W0/W1/W2) -> Wh [N][1536] bf16 = [hi | lo]
__global__ __launch_bounds__(256) void pack_w(const float* __restrict__ W0,
                                              const float* __restrict__ W1,
                                              const float* __restrict__ W2,
                                              int n1, int n2,
                                              ushortT* __restrict__ Wh,
                                              int total4) {
  int g = blockIdx.x * 256 + threadIdx.x;
  if (g >= total4) return;
  int n = g / 192, k4 = (g % 192) * 4;
  const float* src = (n < n1 ? W0 + (size_t)n * 768
                    : n < n2 ? W1 + (size_t)(n - n1) * 768
                             : W2 + (size_t)(n - n2) * 768);
  float4 v = *(const float4*)(src + k4);
  ushortT h[4], l[4];
  split_bf16(v.x, h[0], l[0]);
  split_bf16(v.y, h[1], l[1]);
  split_bf16(v.z, h[2], l[2]);
  split_bf16(v.w, h[3], l[3]);
  ushortT* p = Wh + (size_t)n * KP + k4;
  *(ushort4*)p = *(ushort4*)h;
  *(ushort4*)(p + KH) = *(ushort4*)l;
}

// async global->LDS, 16B per lane; lds base must be wave-uniform (lane*16 implicit)
typedef const __attribute__((address_space(1))) unsigned gq_t;
typedef __attribute__((address_space(3))) unsigned lq_t;
__device__ __forceinline__ void gload_lds16(const ushortT* g, ushortT* l) {
  __builtin_amdgcn_global_load_lds((gq_t*)g, (lq_t*)l, 16, 0, 0);
}

// ---------------- MFMA GEMM: Y[M][N] = A[M][KP] @ B[N][KP]^T (3-term split-bf16) -------
// R9-best (locked): 512 threads / 8 waves, 128x64 tile, 2-phase dbuf. Each wave
// computes a 32x32 quadrant (acc[2][2]); staging split 8 ways, 64B-contiguous
// coalesced segments (4 lanes/row). Row-major LDS (measured conflict-free for b128).
__global__ __launch_bounds__(512, 4) void mfma_gemm(const ushortT* __restrict__ A,
                                                    const ushortT* __restrict__ B,
                                                    float* __restrict__ Y, int ldy,
                                                    int ntiles) {
  __shared__ ushortT sAh[2][128 * 32], sAl[2][128 * 32];
  __shared__ ushortT sBh[2][64 * 32], sBl[2][64 * 32];
  const int blk = blockIdx.x;
  const int xcd = blk & 7, slot = blk >> 3;
  const int mtp = gridDim.x / (8 * ntiles);
  const int mt = xcd * mtp + slot / ntiles;
  const int nt = slot % ntiles;
  const int bm = mt * 128, bn = nt * 64;
  const int tid = threadIdx.x, wave = tid >> 6, lane = tid & 63;
  const int srow = lane >> 2, schk = (lane & 3) * 8;
  const ushortT* gsrc;
  ushortT* lb0;
  ushortT* lb1;
  int iters;
  switch (wave) {
    case 0:  gsrc = A + (size_t)(bm + srow) * KP + schk;           lb0 = sAh[0];        lb1 = sAh[1];        iters = 4; break;
    case 1:  gsrc = A + (size_t)(bm + 64 + srow) * KP + schk;      lb0 = sAh[0] + 2048; lb1 = sAh[1] + 2048; iters = 4; break;
    case 2:  gsrc = A + (size_t)(bm + srow) * KP + KH + schk;      lb0 = sAl[0];        lb1 = sAl[1];        iters = 4; break;
    case 3:  gsrc = A + (size_t)(bm + 64 + srow) * KP + KH + schk; lb0 = sAl[0] + 2048; lb1 = sAl[1] + 2048; iters = 4; break;
    case 4:  gsrc = B + (size_t)(bn + srow) * KP + schk;           lb0 = sBh[0];        lb1 = sBh[1];        iters = 2; break;
    case 5:  gsrc = B + (size_t)(bn + 32 + srow) * KP + schk;      lb0 = sBh[0] + 1024; lb1 = sBh[1] + 1024; iters = 2; break;
    case 6:  gsrc = B + (size_t)(bn + srow) * KP + KH + schk;      lb0 = sBl[0];        lb1 = sBl[1];        iters = 2; break;
    default: gsrc = B + (size_t)(bn + 32 + srow) * KP + KH + schk; lb0 = sBl[0] + 1024; lb1 = sBl[1] + 1024; iters = 2; break;
  }
  const int wm = (wave >> 1) * 32, wn = (wave & 1) * 32;
  const int fr = lane & 15, quad = lane >> 4;
  f32x4 acc[2][2] = {};
  // prologue: stage K-step 0 into buffer 0
  for (int it = 0; it < iters; it++)
    gload_lds16(gsrc + (size_t)it * 16 * KP, lb0 + it * 512);
  __syncthreads();  // vmcnt(0) drain: step-0 tiles landed
#pragma unroll 2
  for (int step = 0; step < 24; step++) {
    const int cur = step & 1;
    // prefetch next K-step into the other buffer (in flight across compute)
    if (step < 23) {
      ushortT* lbn = cur ? lb0 : lb1;
      const int k1 = (step + 1) * 32;
      for (int it = 0; it < iters; it++)
        gload_lds16(gsrc + k1 + (size_t)it * 16 * KP, lbn + it * 512);
    }
    const ushortT* pAh = sAh[cur];
    const ushortT* pAl = sAl[cur];
    const ushortT* pBh = sBh[cur];
    const ushortT* pBl = sBl[cur];
    bf16x8 ah[2], al[2], bh2[2], bl2[2];
#pragma unroll
    for (int mi = 0; mi < 2; mi++) {
      ah[mi] = *(const bf16x8*)&pAh[(wm + mi * 16 + fr) * 32 + quad * 8];
      al[mi] = *(const bf16x8*)&pAl[(wm + mi * 16 + fr) * 32 + quad * 8];
    }
#pragma unroll
    for (int ni = 0; ni < 2; ni++) {
      bh2[ni] = *(const bf16x8*)&pBh[(wn + ni * 16 + fr) * 32 + quad * 8];
      bl2[ni] = *(const bf16x8*)&pBl[(wn + ni * 16 + fr) * 32 + quad * 8];
    }
#pragma unroll
    for (int mi = 0; mi < 2; mi++)
#pragma unroll
      for (int ni = 0; ni < 2; ni++) {
        acc[mi][ni] = __builtin_amdgcn_mfma_f32_16x16x32_bf16(ah[mi], bh2[ni], acc[mi][ni], 0, 0, 0);
        acc[mi][ni] = __builtin_amdgcn_mfma_f32_16x16x32_bf16(ah[mi], bl2[ni], acc[mi][ni], 0, 0, 0);
        acc[mi][ni] = __builtin_amdgcn_mfma_f32_16x16x32_bf16(al[mi], bh2[ni], acc[mi][ni], 0, 0, 0);
      }
    __syncthreads();  // drains vmcnt(0): next-step tiles landed; cur reads done
  }
  const int orow = quad * 4;
#pragma unroll
  for (int mi = 0; mi < 2; mi++)
#pragma unroll
    for (int ni = 0; ni < 2; ni++) {
      float* yp = Y + (size_t)(bm + wm + mi * 16 + orow) * ldy + bn + wn + ni * 16 + fr;
#pragma unroll
      for (int r = 0; r < 4; r++) yp[(size_t)r * ldy] = acc[mi][ni][r];
    }
}

// ---------------- K2: Spk = phi_k^T @ V via MFMA, written packed/transposed/swizzled ----
// R8: 512 threads / 8 waves. phi build split 2 threads/row (VALU halves); MFMA
// retiled 18 row-tiles x 4 col-tiles over 8 waves (9 tiles each, acc[9]).
__global__ __launch_bounds__(512, 4) void chunk_sum_kernel(
    const float* __restrict__ qkv, ushortT* __restrict__ Spk,
    float* __restrict__ csk) {
  const int blk = blockIdx.x;
  const int bh = blk >> 4, c = blk & 15;
  const int b = bh / HH, h = bh % HH;
  __shared__ float kT[16][128];
  __shared__ ushortT phiA[288][72];
  __shared__ ushortT Vt[64][72];
  const float* base = qkv + (size_t)(b * LL + c * CH) * 1152;
  const int tid = threadIdx.x;
  const int wave = tid >> 6, lane = tid & 63;
  const int fr = lane & 15, quad = lane >> 4;
  // kT load: one item per thread (512 items)
  {
    const int m = tid >> 2, i4 = (tid & 3) * 4;
    float4 k4 = *(const float4*)&base[(size_t)m * 1152 + 192 + h * 16 + i4];
    kT[i4 + 0][m] = k4.x; kT[i4 + 1][m] = k4.y;
    kT[i4 + 2][m] = k4.z; kT[i4 + 3][m] = k4.w;
  }
  const int wm2 = (wave & 1) * 144;   // row half: 9 tiles of 16
  const int wn2 = (wave >> 1) * 16;   // col tile: 16 e
  f32x4 acc[9] = {};
  __syncthreads();
#pragma unroll 1
  for (int s = 0; s < 4; s++) {
    const int m0 = s * 32;
    if (s) __syncthreads();
    // Vt stage: one item per thread (512 items)
    {
      const int m = m0 + (tid >> 4), e4 = (tid & 15) * 4;
      float4 v4 = *(const float4*)&base[(size_t)m * 1152 + 384 + h * 64 + e4];
      ushortT hh[4], ll[4];
      split_bf16(v4.x, hh[0], ll[0]); split_bf16(v4.y, hh[1], ll[1]);
      split_bf16(v4.z, hh[2], ll[2]); split_bf16(v4.w, hh[3], ll[3]);
      const int mi2 = m - m0;
#pragma unroll
      for (int j = 0; j < 4; j++) {
        Vt[e4 + j][mi2] = hh[j];
        Vt[e4 + j][32 + mi2] = ll[j];
      }
    }
    // phi build: 576 half-rows (2 threads per feature row, 16 m-values each)
    for (int idx = tid; idx < 576; idx += 512) {
      const int f = idx >> 1, hf = (idx & 1) * 16;
      const float* pa = (f >= 17) ? kT[(f - 17) >> 4] : (f >= 1 ? kT[f - 1] : kT[0]);
      const float* pb = (f >= 17) ? kT[(f - 17) & 15] : kT[0];
      const float sc = (f == 0) ? 1.0f : (f < 17 ? 0.5f : C2f);
      const bool quadf = (f >= 17);
      const bool valid = (f < DEXP);
      ushortT hrow[16], lrow[16];
#pragma unroll
      for (int g = 0; g < 4; g++) {
        float4 a4 = *(const float4*)&pa[m0 + hf + g * 4];
        float4 b4 = *(const float4*)&pb[m0 + hf + g * 4];
        float v0, v1, v2, v3;
        if (f == 0) {
          v0 = v1 = v2 = v3 = 1.0f;
        } else if (!quadf) {
          v0 = sc * a4.x; v1 = sc * a4.y; v2 = sc * a4.z; v3 = sc * a4.w;
        } else {
          v0 = sc * a4.x * b4.x; v1 = sc * a4.y * b4.y;
          v2 = sc * a4.z * b4.z; v3 = sc * a4.w * b4.w;
        }
        if (!valid) { v0 = v1 = v2 = v3 = 0.0f; }
        split_bf16(v0, hrow[g * 4 + 0], lrow[g * 4 + 0]);
        split_bf16(v1, hrow[g * 4 + 1], lrow[g * 4 + 1]);
        split_bf16(v2, hrow[g * 4 + 2], lrow[g * 4 + 2]);
        split_bf16(v3, hrow[g * 4 + 3], lrow[g * 4 + 3]);
      }
      *(uint4*)&phiA[f][hf] = *(uint4*)&hrow[0];
      *(uint4*)&phiA[f][hf + 8] = *(uint4*)&hrow[8];
      *(uint4*)&phiA[f][32 + hf] = *(uint4*)&lrow[0];
      *(uint4*)&phiA[f][32 + hf + 8] = *(uint4*)&lrow[8];
    }
    __syncthreads();
    bf16x8 bhf = *(const bf16x8*)&Vt[wn2 + fr][quad * 8];
    bf16x8 blf = *(const bf16x8*)&Vt[wn2 + fr][32 + quad * 8];
#pragma unroll
    for (int mi = 0; mi < 9; mi++) {
      bf16x8 ah = *(const bf16x8*)&phiA[wm2 + mi * 16 + fr][quad * 8];
      bf16x8 al = *(const bf16x8*)&phiA[wm2 + mi * 16 + fr][32 + quad * 8];
      acc[mi] = __builtin_amdgcn_mfma_f32_16x16x32_bf16(ah, bhf, acc[mi], 0, 0, 0);
      acc[mi] = __builtin_amdgcn_mfma_f32_16x16x32_bf16(ah, blf, acc[mi], 0, 0, 0);
      acc[mi] = __builtin_amdgcn_mfma_f32_16x16x32_bf16(al, bhf, acc[mi], 0, 0, 0);
    }
  }
  for (int f = tid; f < DEXP; f += 512) {
    float sum = 0.0f;
    if (f == 0) {
      sum = (float)CH;
    } else if (f < 17) {
      const float* p = kT[f - 1];
      for (int m = 0; m < CH; m += 4) {
        float4 x = *(const float4*)&p[m];
        sum += x.x + x.y + x.z + x.w;
      }
      sum *= 0.5f;
    } else {
      const float* pa2 = kT[(f - 17) >> 4];
      const float* pb2 = kT[(f - 17) & 15];
      for (int m = 0; m < CH; m += 4) {
        float4 x = *(const float4*)&pa2[m];
        float4 y = *(const float4*)&pb2[m];
        sum += x.x * y.x + x.y * y.y + x.z * y.z + x.w * y.w;
      }
      sum *= C2f;
    }
    csk[(size_t)blk * DEXP + f] = sum;
  }
  // ---- packed epilogue: LDS-transpose per slab (swizzled), then coalesced 16B stream ----
  __syncthreads();  // last MFMA reads of phiA/Vt done before reuse
  ushortT* stage = &phiA[0][0];  // 8KB staging
  ushortT* Sp = Spk + (size_t)blk * SPK_BLK_US;
#pragma unroll 1
  for (int sl = 0; sl < 9; sl++) {
    if (sl) __syncthreads();
#pragma unroll
    for (int mi = 0; mi < 9; mi++) {
      const int fb = wm2 + mi * 16;
      if ((fb >> 5) == sl) {  // wave-uniform
        const int fi0 = (fb & 31) + quad * 4;   // 0..28, mult of 4
        const int gh = fi0 >> 3;                // hi granule 0..3
        const int inner = (fi0 << 1) & 15;      // 0 or 8
        const int e = wn2 + fr;
        const int es = (e & 7) << 4;
        ushortT hh2[4], ll2[4];
#pragma unroll
        for (int r = 0; r < 4; r++) split_bf16(acc[mi][r], hh2[r], ll2[r]);
        char* rowp = (char*)stage + e * 128;
        *(ushort4*)(rowp + ((gh << 4) ^ es) + inner) = *(ushort4*)hh2;
        *(ushort4*)(rowp + (((gh + 4) << 4) ^ es) + inner) = *(ushort4*)ll2;
      }
    }
    __syncthreads();
    uint4* gdst = (uint4*)(Sp + (size_t)sl * SLAB_US);
    const uint4* lsrc = (const uint4*)stage;
    gdst[tid] = lsrc[tid];  // 512 uint4 = 8KB, one per thread
  }
}

// ---------------- K3: across-chunk scan (in place on packed Spk; csk f32) ----------------
__global__ __launch_bounds__(256) void prefix_kernel(ushortT* __restrict__ Spk,
                                                     float* __restrict__ csk) {
  const int gid = blockIdx.x * 256 + threadIdx.x;
  const int totS = NBH * 4608;  // per bh: 9 slab * 64 e * 8 word-pairs
  if (gid < totS) {
    const int bh = gid / 4608;
    const int rem = gid % 4608;
    const int slab = rem >> 9;
    const int e = (rem >> 3) & 63;
    const int wp = rem & 7;
    const int es = (e & 7) << 4;
    const unsigned off_h = e * 128 + ((((wp >> 1)) << 4) ^ es) + ((wp & 1) << 3);
    const unsigned off_l = e * 128 + ((((wp >> 1) + 4) << 4) ^ es) + ((wp & 1) << 3);
    char* base = (char*)Spk + (size_t)bh * NC * SPK_BLK_B + slab * 8192;
    float r0[NC], r1[NC], r2[NC], r3[NC];
    float t0 = 0.f, t1 = 0.f, t2 = 0.f, t3 = 0.f;
#pragma unroll
    for (int cc = 0; cc < NC; cc++) {
      const char* p = base + (size_t)cc * SPK_BLK_B;
      ushort4 hw = *(const ushort4*)(p + off_h);
      ushort4 lw = *(const ushort4*)(p + off_l);
      r0[cc] = __uint_as_float((unsigned)hw.x << 16) + __uint_as_float((unsigned)lw.x << 16);
      r1[cc] = __uint_as_float((unsigned)hw.y << 16) + __uint_as_float((unsigned)lw.y << 16);
      r2[cc] = __uint_as_float((unsigned)hw.z << 16) + __uint_as_float((unsigned)lw.z << 16);
      r3[cc] = __uint_as_float((unsigned)hw.w << 16) + __uint_as_float((unsigned)lw.w << 16);
      t0 += r0[cc]; t1 += r1[cc]; t2 += r2[cc]; t3 += r3[cc];
    }
    float u0 = 0.f, u1 = 0.f, u2 = 0.f, u3 = 0.f;
#pragma unroll
    for (int cc = 0; cc < NC; cc++) {
      ushort4 hw, lw;
      split_bf16(u0 + t0, hw.x, lw.x);
      split_bf16(u1 + t1, hw.y, lw.y);
      split_bf16(u2 + t2, hw.z, lw.z);
      split_bf16(u3 + t3, hw.w, lw.w);
      char* p = base + (size_t)cc * SPK_BLK_B;
      *(ushort4*)(p + off_h) = hw;
      *(ushort4*)(p + off_l) = lw;
      u0 += r0[cc]; u1 += r1[cc]; u2 += r2[cc]; u3 += r3[cc];
    }
  } else {
    const int g2 = gid - totS;
    if (g2 < NBH * DEXP) {
      const int bh = g2 / DEXP;
      const int f = g2 % DEXP;
      float r[NC];
      float tot = 0.0f;
#pragma unroll
      for (int cc = 0; cc < NC; cc++) {
        r[cc] = csk[(size_t)(bh * NC + cc) * DEXP + f];
        tot += r[cc];
      }
      float run = 0.0f;
#pragma unroll
      for (int cc = 0; cc < NC; cc++) {
        csk[(size_t)(bh * NC + cc) * DEXP + f] = run + tot;
        run += r[cc];
      }
    }
  }
}

// ---------------- fused_out: y = [phi(q)@G + P@V] / d, packed to Ahat ----------
// R2/R6-best structure (49.5 µs plateau across 7 variants — closed): 512 thr / 8
// waves, dbuf G-slab prefetch, denominator in MFMA via gk strip + zero-row B-tiles.
__global__ __launch_bounds__(512, 4) void fused_out(
    const float* __restrict__ qkv, const ushortT* __restrict__ Spk,
    const float* __restrict__ csk, ushortT* __restrict__ Ahat) {
  const int blk = blockIdx.x;
  const int bh = blk >> 4, c = blk & 15;
  const int b = bh / HH, h = bh % HH;
  __shared__ ushortT phiA[128][72];  // G-phase: phi(q) A-panel; PV-phase: P A-panel
  __shared__ ushortT GtD[2][4096];   // G-phase: dbuf packed G slab; PV: V^T overlay
  __shared__ ushortT qA1[128][24];   // qhi (K=16 data; K=32 dup synthesized at read)
  __shared__ ushortT qA2[128][24];   // qlo
  __shared__ ushortT kB[32][40];     // [khi|klo] per m-slab
  __shared__ ushortT gkS[9][64];     // per-slab gk strip: [hi(32)|lo(32)]
  __shared__ ushortT zero64[64];     // shared zero B-row
  __shared__ ushortT onesRow[64];    // PV ones B-row: hi=1.0 x32, lo=0
  __shared__ float zl[128];
  const int tid = threadIdx.x;
  const int wv = tid >> 6, lane = tid & 63;
  const int fr = lane & 15, quad = lane >> 4;
  const int prow = tid >> 2, pq = tid & 3;  // 4 threads per row, 8 features each
  const float* base = qkv + (size_t)(b * LL + c * CH) * 1152;
  const float* qrow = base + (size_t)prow * 1152 + h * 16;
  const ushortT* Gp = Spk + (size_t)blk * SPK_BLK_US;
  float qr[16];
#pragma unroll
  for (int i = 0; i < 4; i++) {
    float4 v = *(const float4*)(qrow + i * 4);
    qr[i * 4 + 0] = v.x; qr[i * 4 + 1] = v.y;
    qr[i * 4 + 2] = v.z; qr[i * 4 + 3] = v.w;
  }
  // prefetch slab 0: each wave stages 1KB
  gload_lds16(Gp + wv * 512 + lane * 8, &GtD[0][wv * 512]);
  // qA panels: each thread splits+writes its 4 q-values per panel
  {
    ushortT qh4[4], ql4[4];
#pragma unroll
    for (int i = 0; i < 4; i++) split_bf16(qr[pq * 4 + i], qh4[i], ql4[i]);
    *(ushort4*)&qA1[prow][pq * 4] = *(ushort4*)qh4;
    *(ushort4*)&qA2[prow][pq * 4] = *(ushort4*)ql4;
  }
  // gk strips (scanned inter-chunk k-state) -> LDS, split-bf16
  {
    const float* gkp = csk + (size_t)blk * DEXP;
    for (int f = tid; f < 288; f += 512) {
      float v = (f < DEXP) ? gkp[f] : 0.0f;
      ushortT hh, ll;
      split_bf16(v, hh, ll);
      gkS[f >> 5][f & 31] = hh;
      gkS[f >> 5][32 + (f & 31)] = ll;
    }
  }
  if (tid < 64) {
    zero64[tid] = 0;
    onesRow[tid] = (tid < 32) ? (ushortT)0x3F80 : (ushortT)0;
  }
  f32x4 acc[5] = {};
  // ---------------- G-phase ----------------
#pragma unroll 1
  for (int s = 0; s < 9; s++) {
    __syncthreads();  // slab-s data landed (own vmcnt(0)); prior-buffer reads done
    if (s < 8)
      gload_lds16(Gp + (s + 1) * SLAB_US + wv * 512 + lane * 8,
                  &GtD[(s + 1) & 1][wv * 512]);
    const int f0 = s * 32;
    // stage phi(q) A-panel: 8 features per thread (wave-private rows)
    {
      ushortT h8[8], l8[8];
#pragma unroll
      for (int j = 0; j < 8; j++) {
        const int f = f0 + pq * 8 + j;
        float v;
        if (f == 0) v = 1.0f;
        else if (f < 17) v = 0.5f * qr[f - 1];
        else if (f < DEXP) {
          const int ii = f - 17;
          v = C2f * qr[ii >> 4] * qr[ii & 15];
        } else v = 0.0f;
        split_bf16(v, h8[j], l8[j]);
      }
      *(uint4*)&phiA[prow][pq * 8] = *(uint4*)&h8[0];
      *(uint4*)&phiA[prow][32 + pq * 8] = *(uint4*)&l8[0];
    }
    // same-wave LDS write->read (wave-private rows), no barrier needed
    bf16x8 ah = *(const bf16x8*)&phiA[wv * 16 + fr][quad * 8];
    bf16x8 al = *(const bf16x8*)&phiA[wv * 16 + fr][32 + quad * 8];
    const char* gt = (const char*)&GtD[s & 1][0];
    const int sw = (fr & 7) << 4;  // e&7 == fr&7
#pragma unroll
    for (int ni = 0; ni < 4; ni++) {
      const int rb = (ni * 16 + fr) * 128;
      bf16x8 bh2 = *(const bf16x8*)(gt + rb + ((quad * 16) ^ sw));
      bf16x8 bl2 = *(const bf16x8*)(gt + rb + ((64 + quad * 16) ^ sw));
      acc[ni] = __builtin_amdgcn_mfma_f32_16x16x32_bf16(ah, bh2, acc[ni], 0, 0, 0);
      acc[ni] = __builtin_amdgcn_mfma_f32_16x16x32_bf16(ah, bl2, acc[ni], 0, 0, 0);
      acc[ni] = __builtin_amdgcn_mfma_f32_16x16x32_bf16(al, bh2, acc[ni], 0, 0, 0);
    }
    // denominator column: B col0 = gk strip, cols 1..15 = zero row (per-lane addr)
    {
      const ushortT* gp = (fr == 0) ? &gkS[s][0] : &zero64[0];
      bf16x8 gh = *(const bf16x8*)(gp + quad * 8);
      bf16x8 gl = *(const bf16x8*)(gp + 32 + quad * 8);
      acc[4] = __builtin_amdgcn_mfma_f32_16x16x32_bf16(ah, gh, acc[4], 0, 0, 0);
      acc[4] = __builtin_amdgcn_mfma_f32_16x16x32_bf16(ah, gl, acc[4], 0, 0, 0);
      acc[4] = __builtin_amdgcn_mfma_f32_16x16x32_bf16(al, gh, acc[4], 0, 0, 0);
    }
  }
  __syncthreads();  // G-phase GtD reads done before PV overlays it with V^T
  // ---------------- PV-phase (intra-chunk causal) ----------------
  ushortT* VtF = &GtD[0][0];  // V^T overlay: [64 e][72] rows, flat in GtD
#pragma unroll 1
  for (int s = 0; s < 4; s++) {
    const int m0 = s * 32;
    // stage kB = [khi|klo]
    if (tid < 128) {
      int mL = tid >> 2, i4 = (tid & 3) * 4;
      float4 k4 = *(const float4*)&base[(size_t)(m0 + mL) * 1152 + 192 + h * 16 + i4];
      ushortT hh[4], ll[4];
      split_bf16(k4.x, hh[0], ll[0]); split_bf16(k4.y, hh[1], ll[1]);
      split_bf16(k4.z, hh[2], ll[2]); split_bf16(k4.w, hh[3], ll[3]);
      *(ushort4*)&kB[mL][i4] = *(ushort4*)hh;
      *(ushort4*)&kB[mL][16 + i4] = *(ushort4*)ll;
    }
    // stage V^T slab into VtF
    {
      int mL = tid >> 4, e4 = (tid & 15) * 4;
      float4 v4 = *(const float4*)&base[(size_t)(m0 + mL) * 1152 + 384 + h * 64 + e4];
      ushortT hh[4], ll[4];
      split_bf16(v4.x, hh[0], ll[0]); split_bf16(v4.y, hh[1], ll[1]);
      split_bf16(v4.z, hh[2], ll[2]); split_bf16(v4.w, hh[3], ll[3]);
#pragma unroll
      for (int j = 0; j < 4; j++) {
        VtF[(e4 + j) * 72 + mL] = hh[j];
        VtF[(e4 + j) * 72 + 32 + mL] = ll[j];
      }
    }
    __syncthreads();
    if (s <= (wv >> 1)) {  // causal: slab contributes only to rows >= m0 (wave-uniform)
      // scores -> poly -> mask -> split -> scatter to phiA (wave-private rows)
      bf16x8 a1 = *(const bf16x8*)&qA1[wv * 16 + fr][(quad & 1) * 8];
      bf16x8 a2 = *(const bf16x8*)&qA2[wv * 16 + fr][(quad & 1) * 8];
#pragma unroll
      for (int mtt = 0; mtt < 2; mtt++) {
        bf16x8 bk = *(const bf16x8*)&kB[mtt * 16 + fr][quad * 8];
        f32x4 sf = {};
        sf = __builtin_amdgcn_mfma_f32_16x16x32_bf16(a1, bk, sf, 0, 0, 0);
        sf = __builtin_amdgcn_mfma_f32_16x16x32_bf16(a2, bk, sf, 0, 0, 0);
        const int mg = m0 + mtt * 16 + fr;
#pragma unroll
        for (int r = 0; r < 4; r++) {
          const int rowL = wv * 16 + quad * 4 + r;
          const float sv = sf[r];
          const float p = (mg <= rowL) ? fmaf(sv, fmaf(sv, 0.03125f, 0.25f), 1.0f) : 0.0f;
          ushortT ph, pl;
          split_bf16(p, ph, pl);
          phiA[rowL][mtt * 16 + fr] = ph;
          phiA[rowL][32 + mtt * 16 + fr] = pl;
        }
      }
      // P @ V (+ones col for rowsum) — same-wave LDS dependency, no barrier needed
      bf16x8 ah = *(const bf16x8*)&phiA[wv * 16 + fr][quad * 8];
      bf16x8 al = *(const bf16x8*)&phiA[wv * 16 + fr][32 + quad * 8];
#pragma unroll
      for (int ni = 0; ni < 4; ni++) {
        bf16x8 bh2 = *(const bf16x8*)&VtF[(ni * 16 + fr) * 72 + quad * 8];
        bf16x8 bl2 = *(const bf16x8*)&VtF[(ni * 16 + fr) * 72 + 32 + quad * 8];
        acc[ni] = __builtin_amdgcn_mfma_f32_16x16x32_bf16(ah, bh2, acc[ni], 0, 0, 0);
        acc[ni] = __builtin_amdgcn_mfma_f32_16x16x32_bf16(ah, bl2, acc[ni], 0, 0, 0);
        acc[ni] = __builtin_amdgcn_mfma_f32_16x16x32_bf16(al, bh2, acc[ni], 0, 0, 0);
      }
      {
        const ushortT* op = (fr == 0) ? &onesRow[0] : &zero64[0];
        bf16x8 oh = *(const bf16x8*)(op + quad * 8);
        acc[4] = __builtin_amdgcn_mfma_f32_16x16x32_bf16(ah, oh, acc[4], 0, 0, 0);
        acc[4] = __builtin_amdgcn_mfma_f32_16x16x32_bf16(al, oh, acc[4], 0, 0, 0);
      }
    }
    __syncthreads();
  }
  // ---------------- denominators + epilogue (all wave-private now) ----------------
  if (fr == 0) {
#pragma unroll
    for (int r = 0; r < 4; r++) {
      const int rowL = wv * 16 + quad * 4 + r;
      zl[rowL] = 1.0f / acc[4][r];
    }
  }
  const size_t rowbase = (size_t)(b * LL + c * CH);
#pragma unroll
  for (int ni = 0; ni < 4; ni++)
#pragma unroll
    for (int r = 0; r < 4; r++) {
      const int rowL = wv * 16 + quad * 4 + r;
      const float val = acc[ni][r] * zl[rowL];
      ushortT hh, ll;
      split_bf16(val, hh, ll);
      ushortT* ap = Ahat + (rowbase + rowL) * (size_t)KP + h * 64 + ni * 16 + fr;
      ap[0] = hh;
      ap[KH] = ll;
    }
}

extern "C" void kernel_launch(void* const* d_in, const int* in_sizes, int n_in,
                              void* d_out, int out_size, void* d_ws, size_t ws_size,
                              hipStream_t stream) {
  const float* hs = (const float*)d_in[0];
  const float* Wq = (const float*)d_in[1];
  const float* Wk = (const float*)d_in[2];
  const float* Wv = (const float*)d_in[3];
  const float* Wo = (const float*)d_in[4];
  float* out = (float*)d_out;
  char* ws = (char*)d_ws;
  // layout:
  float* qkv = (float*)(ws);                     // [0, 18874368)
  char*  attR = ws + 18874368;                   // [18874368, 31457280): What -> Ahat
  ushortT* Spk = (ushortT*)(ws + 31457280);      // [31457280, 59768832): packed G (28.3MB)
  float* csk = (float*)(ws + 59768832);          // 419328 -> end 60188160
  ushortT* Xhat = (ushortT*)(ws + 31457280);     // overlays Spk (dead before chunk_sum)
  ushortT* What = (ushortT*)attR;                // 1152*1536*2 = 3.5 MB (dead after QKV gemm)
  ushortT* Ahat = (ushortT*)attR;                // 4096*1536*2 = 12,582,912 (fits region)
  ushortT* Wohat = (ushortT*)qkv;                // 768*1536*2 (written after fused_out)
  const dim3 thr(256);
  // 1) merged input pack: X -> Xhat and Wq/Wk/Wv -> What in ONE launch
  pack_in<<<3936, thr, 0, stream>>>(hs, Xhat, Wq, Wk, Wv, What);
  // 2) fused QKV projection -> qkv fp32 [4096][1152]  (512 thr / 8 waves)
  mfma_gemm<<<576, dim3(512), 0, stream>>>(Xhat, What, qkv, 1152, 18);
  // 3-4) per-chunk sums (packed/swizzled, 512 thr) + across-chunk scan in place
  chunk_sum_kernel<<<NBLK, dim3(512), 0, stream>>>(qkv, Spk, csk);
  {
    const int tot = NBH * 4608 + NBH * DEXP;
    prefix_kernel<<<(tot + 255) / 256, thr, 0, stream>>>(Spk, csk);
  }
  // 5) fused state + intra + scale + pack -> Ahat (512 thr / 8 waves)
  fused_out<<<NBLK, dim3(512), 0, stream>>>(qkv, Spk, csk, Ahat);
  // 6) pack Wo (qkv region dead now)
  pack_w<<<576, thr, 0, stream>>>(Wo, Wo, Wo, 768, 768, Wohat, 768 * 192);
  // 7) output projection (512 thr / 8 waves)
  mfma_gemm<<<384, dim3(512), 0, stream>>>(Ahat, Wohat, out, DM, 12);
}

// Round 15
// 221.020 us; speedup vs baseline: 1.1881x; 1.0208x over previous
//
#include <hip/hip_runtime.h>

typedef unsigned short ushortT;
typedef __bf16 bf16x8 __attribute__((ext_vector_type(8)));
typedef float f32x4 __attribute__((ext_vector_type(4)));

// Problem constants
#define BB   2
#define LL   2048
#define DM   768
#define HH   12
#define FT   16
#define HD   64
#define DEXP 273      // 1 + 16 + 256
#define CH   128      // chunk length
#define NC   16       // chunks per sequence (LL/CH)
#define NBH  24       // BB*HH
#define NBLK 384      // NBH*NC
#define C2f  0.17677669529663687f   // 1/(4*sqrt(2))
#define KH   768      // K per half
#define KP   1536     // packed row length: [hi(768) | lo(768)]
// packed-G geometry: per (bh,chunk): 9 slabs x [64 e][hi fi0..31 | lo fi0..31] ushorts,
// XOR-swizzled: 16B granule g within a 128B e-row lives at g^(e&7).
#define SLAB_US   4096     // ushorts per slab page (64*64)
#define SPK_BLK_US 36864   // 9 slabs
#define SPK_BLK_B  73728

// ---------------- split helpers ----------------
__device__ __forceinline__ void split_bf16(float x, ushortT& hi, ushortT& lo) {
  unsigned b = __float_as_uint(x);
  unsigned r = b + 0x7FFFu + ((b >> 16) & 1u);  // RNE to bf16
  hi = (ushortT)(r >> 16);
  float hf = __uint_as_float((unsigned)hi << 16);
  lo = (ushortT)(__float_as_uint(x - hf) >> 16);  // truncate
}

// Merged input pack: blocks [0,3072) pack X -> Xhat; [3072,3936) pack Wq/Wk/Wv
// -> What; [3936,4512) (only when launched with 4512 blocks) pack Wo -> WoExt.
__global__ __launch_bounds__(256) void pack_in(const float* __restrict__ X,
                                               ushortT* __restrict__ Xh,
                                               const float* __restrict__ W0,
                                               const float* __restrict__ W1,
                                               const float* __restrict__ W2,
                                               ushortT* __restrict__ Wh,
                                               const float* __restrict__ Wo,
                                               ushortT* __restrict__ WoExt) {
  const int blk = blockIdx.x;
  if (blk < 3072) {
    int g = blk * 256 + threadIdx.x;
    if (g >= 4096 * 192) return;
    int m = g / 192, k4 = (g % 192) * 4;
    float4 v = *(const float4*)(X + (size_t)m * 768 + k4);
    ushortT h[4], l[4];
    split_bf16(v.x, h[0], l[0]);
    split_bf16(v.y, h[1], l[1]);
    split_bf16(v.z, h[2], l[2]);
    split_bf16(v.w, h[3], l[3]);
    ushortT* p = Xh + (size_t)m * KP + k4;
    *(ushort4*)p = *(ushort4*)h;
    *(ushort4*)(p + KH) = *(ushort4*)l;
  } else if (blk < 3936) {
    int g = (blk - 3072) * 256 + threadIdx.x;
    if (g >= 1152 * 192) return;
    int n = g / 192, k4 = (g % 192) * 4;
    const float* src = (n < 192 ? W0 + (size_t)n * 768
                      : n < 384 ? W1 + (size_t)(n - 192) * 768
                                : W2 + (size_t)(n - 384) * 768);
    float4 v = *(const float4*)(src + k4);
    ushortT h[4], l[4];
    split_bf16(v.x, h[0], l[0]);
    split_bf16(v.y, h[1], l[1]);
    split_bf16(v.z, h[2], l[2]);
    split_bf16(v.w, h[3], l[3]);
    ushortT* p = Wh + (size_t)n * KP + k4;
    *(ushort4*)p = *(ushort4*)h;
    *(ushort4*)(p + KH) = *(ushort4*)l;
  } else {
    int g = (blk - 3936) * 256 + threadIdx.x;
    if (g >= 768 * 192) return;
    int n = g / 192, k4 = (g % 192) * 4;
    float4 v = *(const float4*)(Wo + (size_t)n * 768 + k4);
    ushortT h[4], l[4];
    split_bf16(v.x, h[0], l[0]);
    split_bf16(v.y, h[1], l[1]);
    split_bf16(v.z, h[2], l[2]);
    split_bf16(v.w, h[3], l[3]);
    ushortT* p = WoExt + (size_t)n * KP + k4;
    *(ushort4*)p = *(ushort4*)h;
    *(ushort4*)(p + KH) = *(ushort4*)l;
  }
}

// W rows (selected from W0/W1/W2) -> Wh [N][1536] bf16 = [hi | lo]
__global__ __launch_bounds__(256) void pack_w(const float* __restrict__ W0,
                                              const float* __restrict__ W1,
                                              const float* __restrict__ W2,
                                              int n1, int n2,
                                              ushortT* __restrict__ Wh,
                                              int total4) {
  int g = blockIdx.x * 256 + threadIdx.x;
  if (g >= total4) return;
  int n = g / 192, k4 = (g % 192) * 4;
  const float* src = (n < n1 ? W0 + (size_t)n * 768
                    : n < n2 ? W1 + (size_t)(n - n1) * 768
                             : W2 + (size_t)(n - n2) * 768);
  float4 v = *(const float4*)(src + k4);
  ushortT h[4], l[4];
  split_bf16(v.x, h[0], l[0]);
  split_bf16(v.y, h[1], l[1]);
  split_bf16(v.z, h[2], l[2]);
  split_bf16(v.w, h[3], l[3]);
  ushortT* p = Wh + (size_t)n * KP + k4;
  *(ushort4*)p = *(ushort4*)h;
  *(ushort4*)(p + KH) = *(ushort4*)l;
}

// async global->LDS, 16B per lane; lds base must be wave-uniform (lane*16 implicit)
typedef const __attribute__((address_space(1))) unsigned gq_t;
typedef __attribute__((address_space(3))) unsigned lq_t;
__device__ __forceinline__ void gload_lds16(const ushortT* g, ushortT* l) {
  __builtin_amdgcn_global_load_lds((gq_t*)g, (lq_t*)l, 16, 0, 0);
}

// ---------------- MFMA GEMM: Y[M][N] = A[M][KP] @ B[N][KP]^T (3-term split-bf16) -------
// R9-best (locked): 512 threads / 8 waves, 128x64 tile, 2-phase dbuf.
__global__ __launch_bounds__(512, 4) void mfma_gemm(const ushortT* __restrict__ A,
                                                    const ushortT* __restrict__ B,
                                                    float* __restrict__ Y, int ldy,
                                                    int ntiles) {
  __shared__ ushortT sAh[2][128 * 32], sAl[2][128 * 32];
  __shared__ ushortT sBh[2][64 * 32], sBl[2][64 * 32];
  const int blk = blockIdx.x;
  const int xcd = blk & 7, slot = blk >> 3;
  const int mtp = gridDim.x / (8 * ntiles);
  const int mt = xcd * mtp + slot / ntiles;
  const int nt = slot % ntiles;
  const int bm = mt * 128, bn = nt * 64;
  const int tid = threadIdx.x, wave = tid >> 6, lane = tid & 63;
  const int srow = lane >> 2, schk = (lane & 3) * 8;
  const ushortT* gsrc;
  ushortT* lb0;
  ushortT* lb1;
  int iters;
  switch (wave) {
    case 0:  gsrc = A + (size_t)(bm + srow) * KP + schk;           lb0 = sAh[0];        lb1 = sAh[1];        iters = 4; break;
    case 1:  gsrc = A + (size_t)(bm + 64 + srow) * KP + schk;      lb0 = sAh[0] + 2048; lb1 = sAh[1] + 2048; iters = 4; break;
    case 2:  gsrc = A + (size_t)(bm + srow) * KP + KH + schk;      lb0 = sAl[0];        lb1 = sAl[1];        iters = 4; break;
    case 3:  gsrc = A + (size_t)(bm + 64 + srow) * KP + KH + schk; lb0 = sAl[0] + 2048; lb1 = sAl[1] + 2048; iters = 4; break;
    case 4:  gsrc = B + (size_t)(bn + srow) * KP + schk;           lb0 = sBh[0];        lb1 = sBh[1];        iters = 2; break;
    case 5:  gsrc = B + (size_t)(bn + 32 + srow) * KP + schk;      lb0 = sBh[0] + 1024; lb1 = sBh[1] + 1024; iters = 2; break;
    case 6:  gsrc = B + (size_t)(bn + srow) * KP + KH + schk;      lb0 = sBl[0];        lb1 = sBl[1];        iters = 2; break;
    default: gsrc = B + (size_t)(bn + 32 + srow) * KP + KH + schk; lb0 = sBl[0] + 1024; lb1 = sBl[1] + 1024; iters = 2; break;
  }
  const int wm = (wave >> 1) * 32, wn = (wave & 1) * 32;
  const int fr = lane & 15, quad = lane >> 4;
  f32x4 acc[2][2] = {};
  // prologue: stage K-step 0 into buffer 0
  for (int it = 0; it < iters; it++)
    gload_lds16(gsrc + (size_t)it * 16 * KP, lb0 + it * 512);
  __syncthreads();  // vmcnt(0) drain: step-0 tiles landed
#pragma unroll 2
  for (int step = 0; step < 24; step++) {
    const int cur = step & 1;
    // prefetch next K-step into the other buffer (in flight across compute)
    if (step < 23) {
      ushortT* lbn = cur ? lb0 : lb1;
      const int k1 = (step + 1) * 32;
      for (int it = 0; it < iters; it++)
        gload_lds16(gsrc + k1 + (size_t)it * 16 * KP, lbn + it * 512);
    }
    const ushortT* pAh = sAh[cur];
    const ushortT* pAl = sAl[cur];
    const ushortT* pBh = sBh[cur];
    const ushortT* pBl = sBl[cur];
    bf16x8 ah[2], al[2], bh2[2], bl2[2];
#pragma unroll
    for (int mi = 0; mi < 2; mi++) {
      ah[mi] = *(const bf16x8*)&pAh[(wm + mi * 16 + fr) * 32 + quad * 8];
      al[mi] = *(const bf16x8*)&pAl[(wm + mi * 16 + fr) * 32 + quad * 8];
    }
#pragma unroll
    for (int ni = 0; ni < 2; ni++) {
      bh2[ni] = *(const bf16x8*)&pBh[(wn + ni * 16 + fr) * 32 + quad * 8];
      bl2[ni] = *(const bf16x8*)&pBl[(wn + ni * 16 + fr) * 32 + quad * 8];
    }
#pragma unroll
    for (int mi = 0; mi < 2; mi++)
#pragma unroll
      for (int ni = 0; ni < 2; ni++) {
        acc[mi][ni] = __builtin_amdgcn_mfma_f32_16x16x32_bf16(ah[mi], bh2[ni], acc[mi][ni], 0, 0, 0);
        acc[mi][ni] = __builtin_amdgcn_mfma_f32_16x16x32_bf16(ah[mi], bl2[ni], acc[mi][ni], 0, 0, 0);
        acc[mi][ni] = __builtin_amdgcn_mfma_f32_16x16x32_bf16(al[mi], bh2[ni], acc[mi][ni], 0, 0, 0);
      }
    __syncthreads();  // drains vmcnt(0): next-step tiles landed; cur reads done
  }
  const int orow = quad * 4;
#pragma unroll
  for (int mi = 0; mi < 2; mi++)
#pragma unroll
    for (int ni = 0; ni < 2; ni++) {
      float* yp = Y + (size_t)(bm + wm + mi * 16 + orow) * ldy + bn + wn + ni * 16 + fr;
#pragma unroll
      for (int r = 0; r < 4; r++) yp[(size_t)r * ldy] = acc[mi][ni][r];
    }
}

// ---------------- K2: Spk = phi_k^T @ V via MFMA, written packed/transposed/swizzled ----
__global__ __launch_bounds__(512, 4) void chunk_sum_kernel(
    const float* __restrict__ qkv, ushortT* __restrict__ Spk,
    float* __restrict__ csk) {
  const int blk = blockIdx.x;
  const int bh = blk >> 4, c = blk & 15;
  const int b = bh / HH, h = bh % HH;
  __shared__ float kT[16][128];
  __shared__ ushortT phiA[288][72];
  __shared__ ushortT Vt[64][72];
  const float* base = qkv + (size_t)(b * LL + c * CH) * 1152;
  const int tid = threadIdx.x;
  const int wave = tid >> 6, lane = tid & 63;
  const int fr = lane & 15, quad = lane >> 4;
  // kT load: one item per thread (512 items)
  {
    const int m = tid >> 2, i4 = (tid & 3) * 4;
    float4 k4 = *(const float4*)&base[(size_t)m * 1152 + 192 + h * 16 + i4];
    kT[i4 + 0][m] = k4.x; kT[i4 + 1][m] = k4.y;
    kT[i4 + 2][m] = k4.z; kT[i4 + 3][m] = k4.w;
  }
  const int wm2 = (wave & 1) * 144;   // row half: 9 tiles of 16
  const int wn2 = (wave >> 1) * 16;   // col tile: 16 e
  f32x4 acc[9] = {};
  __syncthreads();
#pragma unroll 1
  for (int s = 0; s < 4; s++) {
    const int m0 = s * 32;
    if (s) __syncthreads();
    // Vt stage: one item per thread (512 items)
    {
      const int m = m0 + (tid >> 4), e4 = (tid & 15) * 4;
      float4 v4 = *(const float4*)&base[(size_t)m * 1152 + 384 + h * 64 + e4];
      ushortT hh[4], ll[4];
      split_bf16(v4.x, hh[0], ll[0]); split_bf16(v4.y, hh[1], ll[1]);
      split_bf16(v4.z, hh[2], ll[2]); split_bf16(v4.w, hh[3], ll[3]);
      const int mi2 = m - m0;
#pragma unroll
      for (int j = 0; j < 4; j++) {
        Vt[e4 + j][mi2] = hh[j];
        Vt[e4 + j][32 + mi2] = ll[j];
      }
    }
    // phi build: 576 half-rows (2 threads per feature row, 16 m-values each)
    for (int idx = tid; idx < 576; idx += 512) {
      const int f = idx >> 1, hf = (idx & 1) * 16;
      const float* pa = (f >= 17) ? kT[(f - 17) >> 4] : (f >= 1 ? kT[f - 1] : kT[0]);
      const float* pb = (f >= 17) ? kT[(f - 17) & 15] : kT[0];
      const float sc = (f == 0) ? 1.0f : (f < 17 ? 0.5f : C2f);
      const bool quadf = (f >= 17);
      const bool valid = (f < DEXP);
      ushortT hrow[16], lrow[16];
#pragma unroll
      for (int g = 0; g < 4; g++) {
        float4 a4 = *(const float4*)&pa[m0 + hf + g * 4];
        float4 b4 = *(const float4*)&pb[m0 + hf + g * 4];
        float v0, v1, v2, v3;
        if (f == 0) {
          v0 = v1 = v2 = v3 = 1.0f;
        } else if (!quadf) {
          v0 = sc * a4.x; v1 = sc * a4.y; v2 = sc * a4.z; v3 = sc * a4.w;
        } else {
          v0 = sc * a4.x * b4.x; v1 = sc * a4.y * b4.y;
          v2 = sc * a4.z * b4.z; v3 = sc * a4.w * b4.w;
        }
        if (!valid) { v0 = v1 = v2 = v3 = 0.0f; }
        split_bf16(v0, hrow[g * 4 + 0], lrow[g * 4 + 0]);
        split_bf16(v1, hrow[g * 4 + 1], lrow[g * 4 + 1]);
        split_bf16(v2, hrow[g * 4 + 2], lrow[g * 4 + 2]);
        split_bf16(v3, hrow[g * 4 + 3], lrow[g * 4 + 3]);
      }
      *(uint4*)&phiA[f][hf] = *(uint4*)&hrow[0];
      *(uint4*)&phiA[f][hf + 8] = *(uint4*)&hrow[8];
      *(uint4*)&phiA[f][32 + hf] = *(uint4*)&lrow[0];
      *(uint4*)&phiA[f][32 + hf + 8] = *(uint4*)&lrow[8];
    }
    __syncthreads();
    bf16x8 bhf = *(const bf16x8*)&Vt[wn2 + fr][quad * 8];
    bf16x8 blf = *(const bf16x8*)&Vt[wn2 + fr][32 + quad * 8];
#pragma unroll
    for (int mi = 0; mi < 9; mi++) {
      bf16x8 ah = *(const bf16x8*)&phiA[wm2 + mi * 16 + fr][quad * 8];
      bf16x8 al = *(const bf16x8*)&phiA[wm2 + mi * 16 + fr][32 + quad * 8];
      acc[mi] = __builtin_amdgcn_mfma_f32_16x16x32_bf16(ah, bhf, acc[mi], 0, 0, 0);
      acc[mi] = __builtin_amdgcn_mfma_f32_16x16x32_bf16(ah, blf, acc[mi], 0, 0, 0);
      acc[mi] = __builtin_amdgcn_mfma_f32_16x16x32_bf16(al, bhf, acc[mi], 0, 0, 0);
    }
  }
  for (int f = tid; f < DEXP; f += 512) {
    float sum = 0.0f;
    if (f == 0) {
      sum = (float)CH;
    } else if (f < 17) {
      const float* p = kT[f - 1];
      for (int m = 0; m < CH; m += 4) {
        float4 x = *(const float4*)&p[m];
        sum += x.x + x.y + x.z + x.w;
      }
      sum *= 0.5f;
    } else {
      const float* pa2 = kT[(f - 17) >> 4];
      const float* pb2 = kT[(f - 17) & 15];
      for (int m = 0; m < CH; m += 4) {
        float4 x = *(const float4*)&pa2[m];
        float4 y = *(const float4*)&pb2[m];
        sum += x.x * y.x + x.y * y.y + x.z * y.z + x.w * y.w;
      }
      sum *= C2f;
    }
    csk[(size_t)blk * DEXP + f] = sum;
  }
  // ---- packed epilogue: LDS-transpose per slab (swizzled), then coalesced 16B stream ----
  __syncthreads();  // last MFMA reads of phiA/Vt done before reuse
  ushortT* stage = &phiA[0][0];  // 8KB staging
  ushortT* Sp = Spk + (size_t)blk * SPK_BLK_US;
#pragma unroll 1
  for (int sl = 0; sl < 9; sl++) {
    if (sl) __syncthreads();
#pragma unroll
    for (int mi = 0; mi < 9; mi++) {
      const int fb = wm2 + mi * 16;
      if ((fb >> 5) == sl) {  // wave-uniform
        const int fi0 = (fb & 31) + quad * 4;   // 0..28, mult of 4
        const int gh = fi0 >> 3;                // hi granule 0..3
        const int inner = (fi0 << 1) & 15;      // 0 or 8
        const int e = wn2 + fr;
        const int es = (e & 7) << 4;
        ushortT hh2[4], ll2[4];
#pragma unroll
        for (int r = 0; r < 4; r++) split_bf16(acc[mi][r], hh2[r], ll2[r]);
        char* rowp = (char*)stage + e * 128;
        *(ushort4*)(rowp + ((gh << 4) ^ es) + inner) = *(ushort4*)hh2;
        *(ushort4*)(rowp + (((gh + 4) << 4) ^ es) + inner) = *(ushort4*)ll2;
      }
    }
    __syncthreads();
    uint4* gdst = (uint4*)(Sp + (size_t)sl * SLAB_US);
    const uint4* lsrc = (const uint4*)stage;
    gdst[tid] = lsrc[tid];  // 512 uint4 = 8KB, one per thread
  }
}

// ---------------- K3: across-chunk scan (in place on packed Spk; csk f32) ----------------
__global__ __launch_bounds__(256) void prefix_kernel(ushortT* __restrict__ Spk,
                                                     float* __restrict__ csk) {
  const int gid = blockIdx.x * 256 + threadIdx.x;
  const int totS = NBH * 4608;  // per bh: 9 slab * 64 e * 8 word-pairs
  if (gid < totS) {
    const int bh = gid / 4608;
    const int rem = gid % 4608;
    const int slab = rem >> 9;
    const int e = (rem >> 3) & 63;
    const int wp = rem & 7;
    const int es = (e & 7) << 4;
    const unsigned off_h = e * 128 + ((((wp >> 1)) << 4) ^ es) + ((wp & 1) << 3);
    const unsigned off_l = e * 128 + ((((wp >> 1) + 4) << 4) ^ es) + ((wp & 1) << 3);
    char* base = (char*)Spk + (size_t)bh * NC * SPK_BLK_B + slab * 8192;
    float r0[NC], r1[NC], r2[NC], r3[NC];
    float t0 = 0.f, t1 = 0.f, t2 = 0.f, t3 = 0.f;
#pragma unroll
    for (int cc = 0; cc < NC; cc++) {
      const char* p = base + (size_t)cc * SPK_BLK_B;
      ushort4 hw = *(const ushort4*)(p + off_h);
      ushort4 lw = *(const ushort4*)(p + off_l);
      r0[cc] = __uint_as_float((unsigned)hw.x << 16) + __uint_as_float((unsigned)lw.x << 16);
      r1[cc] = __uint_as_float((unsigned)hw.y << 16) + __uint_as_float((unsigned)lw.y << 16);
      r2[cc] = __uint_as_float((unsigned)hw.z << 16) + __uint_as_float((unsigned)lw.z << 16);
      r3[cc] = __uint_as_float((unsigned)hw.w << 16) + __uint_as_float((unsigned)lw.w << 16);
      t0 += r0[cc]; t1 += r1[cc]; t2 += r2[cc]; t3 += r3[cc];
    }
    float u0 = 0.f, u1 = 0.f, u2 = 0.f, u3 = 0.f;
#pragma unroll
    for (int cc = 0; cc < NC; cc++) {
      ushort4 hw, lw;
      split_bf16(u0 + t0, hw.x, lw.x);
      split_bf16(u1 + t1, hw.y, lw.y);
      split_bf16(u2 + t2, hw.z, lw.z);
      split_bf16(u3 + t3, hw.w, lw.w);
      char* p = base + (size_t)cc * SPK_BLK_B;
      *(ushort4*)(p + off_h) = hw;
      *(ushort4*)(p + off_l) = lw;
      u0 += r0[cc]; u1 += r1[cc]; u2 += r2[cc]; u3 += r3[cc];
    }
  } else {
    const int g2 = gid - totS;
    if (g2 < NBH * DEXP) {
      const int bh = g2 / DEXP;
      const int f = g2 % DEXP;
      float r[NC];
      float tot = 0.0f;
#pragma unroll
      for (int cc = 0; cc < NC; cc++) {
        r[cc] = csk[(size_t)(bh * NC + cc) * DEXP + f];
        tot += r[cc];
      }
      float run = 0.0f;
#pragma unroll
      for (int cc = 0; cc < NC; cc++) {
        csk[(size_t)(bh * NC + cc) * DEXP + f] = run + tot;
        run += r[cc];
      }
    }
  }
}

// ---------------- fused_out: y = [phi(q)@G + P@V] / d, packed to Ahat ----------
// R2/R6-best structure (49.5 µs plateau across 7 variants — closed).
__global__ __launch_bounds__(512, 4) void fused_out(
    const float* __restrict__ qkv, const ushortT* __restrict__ Spk,
    const float* __restrict__ csk, ushortT* __restrict__ Ahat) {
  const int blk = blockIdx.x;
  const int bh = blk >> 4, c = blk & 15;
  const int b = bh / HH, h = bh % HH;
  __shared__ ushortT phiA[128][72];  // G-phase: phi(q) A-panel; PV-phase: P A-panel
  __shared__ ushortT GtD[2][4096];   // G-phase: dbuf packed G slab; PV: V^T overlay
  __shared__ ushortT qA1[128][24];   // qhi (K=16 data; K=32 dup synthesized at read)
  __shared__ ushortT qA2[128][24];   // qlo
  __shared__ ushortT kB[32][40];     // [khi|klo] per m-slab
  __shared__ ushortT gkS[9][64];     // per-slab gk strip: [hi(32)|lo(32)]
  __shared__ ushortT zero64[64];     // shared zero B-row
  __shared__ ushortT onesRow[64];    // PV ones B-row: hi=1.0 x32, lo=0
  __shared__ float zl[128];
  const int tid = threadIdx.x;
  const int wv = tid >> 6, lane = tid & 63;
  const int fr = lane & 15, quad = lane >> 4;
  const int prow = tid >> 2, pq = tid & 3;  // 4 threads per row, 8 features each
  const float* base = qkv + (size_t)(b * LL + c * CH) * 1152;
  const float* qrow = base + (size_t)prow * 1152 + h * 16;
  const ushortT* Gp = Spk + (size_t)blk * SPK_BLK_US;
  float qr[16];
#pragma unroll
  for (int i = 0; i < 4; i++) {
    float4 v = *(const float4*)(qrow + i * 4);
    qr[i * 4 + 0] = v.x; qr[i * 4 + 1] = v.y;
    qr[i * 4 + 2] = v.z; qr[i * 4 + 3] = v.w;
  }
  // prefetch slab 0: each wave stages 1KB
  gload_lds16(Gp + wv * 512 + lane * 8, &GtD[0][wv * 512]);
  // qA panels: each thread splits+writes its 4 q-values per panel
  {
    ushortT qh4[4], ql4[4];
#pragma unroll
    for (int i = 0; i < 4; i++) split_bf16(qr[pq * 4 + i], qh4[i], ql4[i]);
    *(ushort4*)&qA1[prow][pq * 4] = *(ushort4*)qh4;
    *(ushort4*)&qA2[prow][pq * 4] = *(ushort4*)ql4;
  }
  // gk strips (scanned inter-chunk k-state) -> LDS, split-bf16
  {
    const float* gkp = csk + (size_t)blk * DEXP;
    for (int f = tid; f < 288; f += 512) {
      float v = (f < DEXP) ? gkp[f] : 0.0f;
      ushortT hh, ll;
      split_bf16(v, hh, ll);
      gkS[f >> 5][f & 31] = hh;
      gkS[f >> 5][32 + (f & 31)] = ll;
    }
  }
  if (tid < 64) {
    zero64[tid] = 0;
    onesRow[tid] = (tid < 32) ? (ushortT)0x3F80 : (ushortT)0;
  }
  f32x4 acc[5] = {};
  // ---------------- G-phase ----------------
#pragma unroll 1
  for (int s = 0; s < 9; s++) {
    __syncthreads();  // slab-s data landed (own vmcnt(0)); prior-buffer reads done
    if (s < 8)
      gload_lds16(Gp + (s + 1) * SLAB_US + wv * 512 + lane * 8,
                  &GtD[(s + 1) & 1][wv * 512]);
    const int f0 = s * 32;
    // stage phi(q) A-panel: 8 features per thread (wave-private rows)
    {
      ushortT h8[8], l8[8];
#pragma unroll
      for (int j = 0; j < 8; j++) {
        const int f = f0 + pq * 8 + j;
        float v;
        if (f == 0) v = 1.0f;
        else if (f < 17) v = 0.5f * qr[f - 1];
        else if (f < DEXP) {
          const int ii = f - 17;
          v = C2f * qr[ii >> 4] * qr[ii & 15];
        } else v = 0.0f;
        split_bf16(v, h8[j], l8[j]);
      }
      *(uint4*)&phiA[prow][pq * 8] = *(uint4*)&h8[0];
      *(uint4*)&phiA[prow][32 + pq * 8] = *(uint4*)&l8[0];
    }
    // same-wave LDS write->read (wave-private rows), no barrier needed
    bf16x8 ah = *(const bf16x8*)&phiA[wv * 16 + fr][quad * 8];
    bf16x8 al = *(const bf16x8*)&phiA[wv * 16 + fr][32 + quad * 8];
    const char* gt = (const char*)&GtD[s & 1][0];
    const int sw = (fr & 7) << 4;  // e&7 == fr&7
#pragma unroll
    for (int ni = 0; ni < 4; ni++) {
      const int rb = (ni * 16 + fr) * 128;
      bf16x8 bh2 = *(const bf16x8*)(gt + rb + ((quad * 16) ^ sw));
      bf16x8 bl2 = *(const bf16x8*)(gt + rb + ((64 + quad * 16) ^ sw));
      acc[ni] = __builtin_amdgcn_mfma_f32_16x16x32_bf16(ah, bh2, acc[ni], 0, 0, 0);
      acc[ni] = __builtin_amdgcn_mfma_f32_16x16x32_bf16(ah, bl2, acc[ni], 0, 0, 0);
      acc[ni] = __builtin_amdgcn_mfma_f32_16x16x32_bf16(al, bh2, acc[ni], 0, 0, 0);
    }
    // denominator column: B col0 = gk strip, cols 1..15 = zero row (per-lane addr)
    {
      const ushortT* gp = (fr == 0) ? &gkS[s][0] : &zero64[0];
      bf16x8 gh = *(const bf16x8*)(gp + quad * 8);
      bf16x8 gl = *(const bf16x8*)(gp + 32 + quad * 8);
      acc[4] = __builtin_amdgcn_mfma_f32_16x16x32_bf16(ah, gh, acc[4], 0, 0, 0);
      acc[4] = __builtin_amdgcn_mfma_f32_16x16x32_bf16(ah, gl, acc[4], 0, 0, 0);
      acc[4] = __builtin_amdgcn_mfma_f32_16x16x32_bf16(al, gh, acc[4], 0, 0, 0);
    }
  }
  __syncthreads();  // G-phase GtD reads done before PV overlays it with V^T
  // ---------------- PV-phase (intra-chunk causal) ----------------
  ushortT* VtF = &GtD[0][0];  // V^T overlay: [64 e][72] rows, flat in GtD
#pragma unroll 1
  for (int s = 0; s < 4; s++) {
    const int m0 = s * 32;
    // stage kB = [khi|klo]
    if (tid < 128) {
      int mL = tid >> 2, i4 = (tid & 3) * 4;
      float4 k4 = *(const float4*)&base[(size_t)(m0 + mL) * 1152 + 192 + h * 16 + i4];
      ushortT hh[4], ll[4];
      split_bf16(k4.x, hh[0], ll[0]); split_bf16(k4.y, hh[1], ll[1]);
      split_bf16(k4.z, hh[2], ll[2]); split_bf16(k4.w, hh[3], ll[3]);
      *(ushort4*)&kB[mL][i4] = *(ushort4*)hh;
      *(ushort4*)&kB[mL][16 + i4] = *(ushort4*)ll;
    }
    // stage V^T slab into VtF
    {
      int mL = tid >> 4, e4 = (tid & 15) * 4;
      float4 v4 = *(const float4*)&base[(size_t)(m0 + mL) * 1152 + 384 + h * 64 + e4];
      ushortT hh[4], ll[4];
      split_bf16(v4.x, hh[0], ll[0]); split_bf16(v4.y, hh[1], ll[1]);
      split_bf16(v4.z, hh[2], ll[2]); split_bf16(v4.w, hh[3], ll[3]);
#pragma unroll
      for (int j = 0; j < 4; j++) {
        VtF[(e4 + j) * 72 + mL] = hh[j];
        VtF[(e4 + j) * 72 + 32 + mL] = ll[j];
      }
    }
    __syncthreads();
    if (s <= (wv >> 1)) {  // causal: slab contributes only to rows >= m0 (wave-uniform)
      // scores -> poly -> mask -> split -> scatter to phiA (wave-private rows)
      bf16x8 a1 = *(const bf16x8*)&qA1[wv * 16 + fr][(quad & 1) * 8];
      bf16x8 a2 = *(const bf16x8*)&qA2[wv * 16 + fr][(quad & 1) * 8];
#pragma unroll
      for (int mtt = 0; mtt < 2; mtt++) {
        bf16x8 bk = *(const bf16x8*)&kB[mtt * 16 + fr][quad * 8];
        f32x4 sf = {};
        sf = __builtin_amdgcn_mfma_f32_16x16x32_bf16(a1, bk, sf, 0, 0, 0);
        sf = __builtin_amdgcn_mfma_f32_16x16x32_bf16(a2, bk, sf, 0, 0, 0);
        const int mg = m0 + mtt * 16 + fr;
#pragma unroll
        for (int r = 0; r < 4; r++) {
          const int rowL = wv * 16 + quad * 4 + r;
          const float sv = sf[r];
          const float p = (mg <= rowL) ? fmaf(sv, fmaf(sv, 0.03125f, 0.25f), 1.0f) : 0.0f;
          ushortT ph, pl;
          split_bf16(p, ph, pl);
          phiA[rowL][mtt * 16 + fr] = ph;
          phiA[rowL][32 + mtt * 16 + fr] = pl;
        }
      }
      // P @ V (+ones col for rowsum) — same-wave LDS dependency, no barrier needed
      bf16x8 ah = *(const bf16x8*)&phiA[wv * 16 + fr][quad * 8];
      bf16x8 al = *(const bf16x8*)&phiA[wv * 16 + fr][32 + quad * 8];
#pragma unroll
      for (int ni = 0; ni < 4; ni++) {
        bf16x8 bh2 = *(const bf16x8*)&VtF[(ni * 16 + fr) * 72 + quad * 8];
        bf16x8 bl2 = *(const bf16x8*)&VtF[(ni * 16 + fr) * 72 + 32 + quad * 8];
        acc[ni] = __builtin_amdgcn_mfma_f32_16x16x32_bf16(ah, bh2, acc[ni], 0, 0, 0);
        acc[ni] = __builtin_amdgcn_mfma_f32_16x16x32_bf16(ah, bl2, acc[ni], 0, 0, 0);
        acc[ni] = __builtin_amdgcn_mfma_f32_16x16x32_bf16(al, bh2, acc[ni], 0, 0, 0);
      }
      {
        const ushortT* op = (fr == 0) ? &onesRow[0] : &zero64[0];
        bf16x8 oh = *(const bf16x8*)(op + quad * 8);
        acc[4] = __builtin_amdgcn_mfma_f32_16x16x32_bf16(ah, oh, acc[4], 0, 0, 0);
        acc[4] = __builtin_amdgcn_mfma_f32_16x16x32_bf16(al, oh, acc[4], 0, 0, 0);
      }
    }
    __syncthreads();
  }
  // ---------------- denominators + epilogue (all wave-private now) ----------------
  if (fr == 0) {
#pragma unroll
    for (int r = 0; r < 4; r++) {
      const int rowL = wv * 16 + quad * 4 + r;
      zl[rowL] = 1.0f / acc[4][r];
    }
  }
  const size_t rowbase = (size_t)(b * LL + c * CH);
#pragma unroll
  for (int ni = 0; ni < 4; ni++)
#pragma unroll
    for (int r = 0; r < 4; r++) {
      const int rowL = wv * 16 + quad * 4 + r;
      const float val = acc[ni][r] * zl[rowL];
      ushortT hh, ll;
      split_bf16(val, hh, ll);
      ushortT* ap = Ahat + (rowbase + rowL) * (size_t)KP + h * 64 + ni * 16 + fr;
      ap[0] = hh;
      ap[KH] = ll;
    }
}

extern "C" void kernel_launch(void* const* d_in, const int* in_sizes, int n_in,
                              void* d_out, int out_size, void* d_ws, size_t ws_size,
                              hipStream_t stream) {
  const float* hs = (const float*)d_in[0];
  const float* Wq = (const float*)d_in[1];
  const float* Wk = (const float*)d_in[2];
  const float* Wv = (const float*)d_in[3];
  const float* Wo = (const float*)d_in[4];
  float* out = (float*)d_out;
  char* ws = (char*)d_ws;
  // layout:
  float* qkv = (float*)(ws);                     // [0, 18874368)
  char*  attR = ws + 18874368;                   // [18874368, 31457280): What -> Ahat
  ushortT* Spk = (ushortT*)(ws + 31457280);      // [31457280, 59768832): packed G (28.3MB)
  float* csk = (float*)(ws + 59768832);          // 419328 -> end 60188160
  ushortT* Xhat = (ushortT*)(ws + 31457280);     // overlays Spk (dead before chunk_sum)
  ushortT* What = (ushortT*)attR;                // 1152*1536*2 = 3.5 MB (dead after QKV gemm)
  ushortT* Ahat = (ushortT*)attR;                // 4096*1536*2 = 12,582,912 (fits region)
  ushortT* Wohat = (ushortT*)qkv;                // 768*1536*2 (fallback: qkv region)
  const size_t baseEnd = 60188160;
  const size_t woBytes = (size_t)768 * KP * 2;   // 2,359,296
  const bool extWo = (ws_size >= baseEnd + woBytes);
  ushortT* WoExt = (ushortT*)(ws + baseEnd);     // used only when extWo
  const dim3 thr(256);
  if (extWo) {
    // 1) merged pack: X -> Xhat, Wq/Wk/Wv -> What, Wo -> WoExt — ONE launch
    pack_in<<<4512, thr, 0, stream>>>(hs, Xhat, Wq, Wk, Wv, What, Wo, WoExt);
  } else {
    pack_in<<<3936, thr, 0, stream>>>(hs, Xhat, Wq, Wk, Wv, What, Wo, WoExt);
  }
  // 2) fused QKV projection -> qkv fp32 [4096][1152]  (512 thr / 8 waves)
  mfma_gemm<<<576, dim3(512), 0, stream>>>(Xhat, What, qkv, 1152, 18);
  // 3-4) per-chunk sums (packed/swizzled, 512 thr) + across-chunk scan in place
  chunk_sum_kernel<<<NBLK, dim3(512), 0, stream>>>(qkv, Spk, csk);
  {
    const int tot = NBH * 4608 + NBH * DEXP;
    prefix_kernel<<<(tot + 255) / 256, thr, 0, stream>>>(Spk, csk);
  }
  // 5) fused state + intra + scale + pack -> Ahat (512 thr / 8 waves)
  fused_out<<<NBLK, dim3(512), 0, stream>>>(qkv, Spk, csk, Ahat);
  if (extWo) {
    // 6) output projection directly (Wo already packed in step 1)
    mfma_gemm<<<384, dim3(512), 0, stream>>>(Ahat, WoExt, out, DM, 12);
  } else {
    // 6) pack Wo (qkv region dead now), then output projection
    pack_w<<<576, thr, 0, stream>>>(Wo, Wo, Wo, 768, 768, Wohat, 768 * 192);
    mfma_gemm<<<384, dim3(512), 0, stream>>>(Ahat, Wohat, out, DM, 12);
  }
}